// Round 3
// baseline (1868.638 us; speedup 1.0000x reference)
//
#include <hip/hip_runtime.h>
#include <math.h>

// ---------------------------------------------------------------------------
// GraphNet: 3x EdgeConv (fully linearized, gather fused into tiled GEMM)
//          + GAT(2 heads, concat=False)
//
// EdgeConv layer l:  out = relu( A_ext @ W_ext )   per 64-row tile, K=72:
//   A_ext[r][0:64]  = Σ_{e→r} h[src_e]      (gathered into LDS, phase 1)
//   A_ext[r][64:69] = B5[r] (Σ edge_attr)    A_ext[r][69] = deg[r]
//   W_ext[0:64]     = wn@wc_top              W_ext[64:69] = we@wc_bot
//   W_ext[69]       = bn@wc_top + be@wc_bot + bc
// ---------------------------------------------------------------------------

#define TPB 256

// 16 FMAs: acc(4 cols) += sum_j a.comp_j * w_j(4 cols)
#define MAC4(acc, a, w0, w1, w2, w3)                                           \
    acc.x = fmaf(a.x, w0.x, acc.x); acc.y = fmaf(a.x, w0.y, acc.y);            \
    acc.z = fmaf(a.x, w0.z, acc.z); acc.w = fmaf(a.x, w0.w, acc.w);            \
    acc.x = fmaf(a.y, w1.x, acc.x); acc.y = fmaf(a.y, w1.y, acc.y);            \
    acc.z = fmaf(a.y, w1.z, acc.z); acc.w = fmaf(a.y, w1.w, acc.w);            \
    acc.x = fmaf(a.z, w2.x, acc.x); acc.y = fmaf(a.z, w2.y, acc.y);            \
    acc.z = fmaf(a.z, w2.z, acc.z); acc.w = fmaf(a.z, w2.w, acc.w);            \
    acc.x = fmaf(a.w, w3.x, acc.x); acc.y = fmaf(a.w, w3.y, acc.y);            \
    acc.z = fmaf(a.w, w3.z, acc.z); acc.w = fmaf(a.w, w3.w, acc.w);

// ---------------- CSR build ----------------
__global__ __launch_bounds__(TPB) void k_hist(const int* __restrict__ dst, int* __restrict__ deg, int E) {
    int e = blockIdx.x * TPB + threadIdx.x;
    if (e < E) atomicAdd(&deg[dst[e]], 1);
}

__global__ __launch_bounds__(TPB) void k_scan1(int* __restrict__ data, int* __restrict__ partials, int n) {
    __shared__ int s[TPB];
    int i = blockIdx.x * TPB + threadIdx.x;
    int v = (i < n) ? data[i] : 0;
    s[threadIdx.x] = v;
    __syncthreads();
    for (int off = 1; off < TPB; off <<= 1) {
        int t = (threadIdx.x >= off) ? s[threadIdx.x - off] : 0;
        __syncthreads();
        s[threadIdx.x] += t;
        __syncthreads();
    }
    if (i < n) data[i] = s[threadIdx.x] - v;  // exclusive
    if (threadIdx.x == TPB - 1) partials[blockIdx.x] = s[TPB - 1];
}

__global__ __launch_bounds__(1024) void k_scan2(int* __restrict__ partials, int nb) {
    __shared__ int s[1024];
    int v = (threadIdx.x < nb) ? partials[threadIdx.x] : 0;
    s[threadIdx.x] = v;
    __syncthreads();
    for (int off = 1; off < 1024; off <<= 1) {
        int t = (threadIdx.x >= off) ? s[threadIdx.x - off] : 0;
        __syncthreads();
        s[threadIdx.x] += t;
        __syncthreads();
    }
    if (threadIdx.x < nb) partials[threadIdx.x] = s[threadIdx.x] - v;  // exclusive
}

__global__ __launch_bounds__(TPB) void k_scan3(int* __restrict__ data, const int* __restrict__ partials,
                                               int* __restrict__ cursor, int n, int total) {
    int i = blockIdx.x * TPB + threadIdx.x;
    if (i < n) {
        int v = data[i] + partials[blockIdx.x];
        data[i] = v;
        cursor[i] = v;
    }
    if (i == 0) data[n] = total;
}

__global__ __launch_bounds__(TPB) void k_scatter(const int* __restrict__ src, const int* __restrict__ dst,
                                                 int* __restrict__ cursor, int* __restrict__ csr_e,
                                                 int* __restrict__ csr_src, int E) {
    int e = blockIdx.x * TPB + threadIdx.x;
    if (e < E) {
        int d = dst[e];
        int idx = atomicAdd(&cursor[d], 1);
        csr_e[idx] = e;
        csr_src[idx] = src[e];
    }
}

// ---------------- weight folding (per layer, 1 block) ----------------
__global__ __launch_bounds__(TPB) void k_combine(const float* __restrict__ wn, const float* __restrict__ bn,
                                                 const float* __restrict__ we, const float* __restrict__ be,
                                                 const float* __restrict__ wc, const float* __restrict__ bc,
                                                 float* __restrict__ W1, float* __restrict__ W2,
                                                 float* __restrict__ cv) {
    int tid = threadIdx.x;
    for (int idx = tid; idx < 64 * 64; idx += TPB) {
        int i = idx >> 6, j = idx & 63;
        float acc = 0.f;
        #pragma unroll 8
        for (int k = 0; k < 64; k++) acc = fmaf(wn[i * 64 + k], wc[k * 64 + j], acc);
        W1[idx] = acc;
    }
    for (int idx = tid; idx < 5 * 64; idx += TPB) {
        int i = idx >> 6, j = idx & 63;
        float acc = 0.f;
        #pragma unroll 8
        for (int k = 0; k < 64; k++) acc = fmaf(we[i * 64 + k], wc[(64 + k) * 64 + j], acc);
        W2[idx] = acc;
    }
    for (int j = tid; j < 64; j += TPB) {
        float acc = bc[j];
        for (int k = 0; k < 64; k++) {
            acc = fmaf(bn[k], wc[k * 64 + j], acc);
            acc = fmaf(be[k], wc[(64 + k) * 64 + j], acc);
        }
        cv[j] = acc;
    }
}

// ---------------- B5[d] = sum of ea over incoming edges (once) ----------------
__global__ __launch_bounds__(TPB) void k_aggB5(const int* __restrict__ row_start, const int* __restrict__ csr_e,
                                               const float* __restrict__ EA, float* __restrict__ B5, int n) {
    int wave = threadIdx.x >> 6, lane = threadIdx.x & 63;
    for (int node = blockIdx.x * 4 + wave; node < n; node += gridDim.x * 4) {
        int beg = row_start[node], end = row_start[node + 1];
        float b0 = 0.f, b1 = 0.f, b2 = 0.f, b3 = 0.f, b4 = 0.f;
        for (int chunk = beg; chunk < end; chunk += 64) {
            int j = chunk + lane;
            if (j < end) {
                int e = csr_e[j];
                const float* eap = EA + (size_t)e * 5;
                b0 += eap[0]; b1 += eap[1]; b2 += eap[2]; b3 += eap[3]; b4 += eap[4];
            }
        }
        #pragma unroll
        for (int off = 1; off < 64; off <<= 1) {
            b0 += __shfl_xor(b0, off);
            b1 += __shfl_xor(b1, off);
            b2 += __shfl_xor(b2, off);
            b3 += __shfl_xor(b3, off);
            b4 += __shfl_xor(b4, off);
        }
        if (lane == 0) {
            float* bp = B5 + (size_t)node * 5;
            bp[0] = b0; bp[1] = b1; bp[2] = b2; bp[3] = b3; bp[4] = b4;
        }
    }
}

// ---------------- fused EdgeConv layer: gather -> LDS -> tiled GEMM ----------
// block = one 64-node tile. LDS: A_ext[64][76] (K=72 + bank pad), W_ext[72][68].
__global__ __launch_bounds__(TPB) void k_ec_layer(const float* __restrict__ H,
                                                  const int* __restrict__ row_start,
                                                  const int* __restrict__ csr_src,
                                                  const float* __restrict__ B5,
                                                  const float* __restrict__ Wfold,  // W1(4096)|W2(320)|cv(64)
                                                  float* __restrict__ OUT, int n) {
    __shared__ float Alds[64 * 76];
    __shared__ float Wlds[72 * 68];
    const int t = threadIdx.x;
    const int base = blockIdx.x * 64;

    // ---- stage W_ext [72][68] ----
    {
        int r16 = t >> 4, cc = (t & 15) * 4;
        #pragma unroll
        for (int rep = 0; rep < 4; rep++) {
            int r = rep * 16 + r16;
            *(float4*)&Wlds[r * 68 + cc] = *(const float4*)&Wfold[r * 64 + cc];
        }
        if (t < 128) {
            int idx4 = t * 4;                 // 0..508 -> rows 64..71
            int r = 64 + (idx4 >> 6), c = idx4 & 63;
            float4 v = make_float4(0.f, 0.f, 0.f, 0.f);
            if (r < 70) v = *(const float4*)&Wfold[4096 + (r - 64) * 64 + c];  // W2 rows + cv row
            *(float4*)&Wlds[r * 68 + c] = v;
        }
    }

    // ---- phase 1: gather A_ext (each wave owns 16 rows) ----
    const int wave = t >> 6, lane = t & 63;
    const int g = lane >> 4, c4 = (lane & 15) * 4;
    for (int i = 0; i < 16; i++) {
        int nl = wave * 16 + i;
        int node = base + nl;
        int beg = 0, end = 0;
        if (node < n) { beg = row_start[node]; end = row_start[node + 1]; }
        float ax = 0.f, ay = 0.f, az = 0.f, aw = 0.f;
        for (int chunk = beg; chunk < end; chunk += 64) {
            int cdeg = min(end - chunk, 64);
            int s_l = (chunk + lane < end) ? csr_src[chunk + lane] : 0;
            int iters = (cdeg + 3) >> 2;
            for (int it = 0; it < iters; it++) {
                int el = g + 4 * it;
                int se = __shfl(s_l, el);
                if (el < cdeg) {
                    const float4 v = *(const float4*)&H[(size_t)se * 64 + c4];
                    ax += v.x; ay += v.y; az += v.z; aw += v.w;
                }
            }
        }
        ax += __shfl_xor(ax, 16); ay += __shfl_xor(ay, 16); az += __shfl_xor(az, 16); aw += __shfl_xor(aw, 16);
        ax += __shfl_xor(ax, 32); ay += __shfl_xor(ay, 32); az += __shfl_xor(az, 32); aw += __shfl_xor(aw, 32);
        if (g == 0) {
            float4 r4; r4.x = ax; r4.y = ay; r4.z = az; r4.w = aw;
            *(float4*)&Alds[nl * 76 + c4] = r4;
        }
        if (lane >= 16 && lane < 24) {
            int j = lane - 16;                // ext cols 64..71
            float v = 0.f;
            if (node < n) {
                if (j < 5) v = B5[(size_t)node * 5 + j];
                else if (j == 5) v = (float)(end - beg);
            }
            Alds[nl * 76 + 64 + j] = v;
        }
    }
    __syncthreads();

    // ---- phase 2: GEMM 64x72 * 72x64, 4x4 micro-tile per thread ----
    const int r0 = (t >> 4) * 4, c0 = (t & 15) * 4;
    float4 acc0 = make_float4(0.f, 0.f, 0.f, 0.f), acc1 = acc0, acc2 = acc0, acc3 = acc0;
    #pragma unroll
    for (int k = 0; k < 72; k += 4) {
        float4 a0 = *(float4*)&Alds[(r0 + 0) * 76 + k];
        float4 a1 = *(float4*)&Alds[(r0 + 1) * 76 + k];
        float4 a2 = *(float4*)&Alds[(r0 + 2) * 76 + k];
        float4 a3 = *(float4*)&Alds[(r0 + 3) * 76 + k];
        float4 w0 = *(float4*)&Wlds[(k + 0) * 68 + c0];
        float4 w1 = *(float4*)&Wlds[(k + 1) * 68 + c0];
        float4 w2 = *(float4*)&Wlds[(k + 2) * 68 + c0];
        float4 w3 = *(float4*)&Wlds[(k + 3) * 68 + c0];
        MAC4(acc0, a0, w0, w1, w2, w3);
        MAC4(acc1, a1, w0, w1, w2, w3);
        MAC4(acc2, a2, w0, w1, w2, w3);
        MAC4(acc3, a3, w0, w1, w2, w3);
    }
    #define EC_STORE(i, acc)                                                        \
        { int row = base + r0 + i;                                                  \
          if (row < n) {                                                            \
              float4 r4;                                                            \
              r4.x = fmaxf(acc.x, 0.f); r4.y = fmaxf(acc.y, 0.f);                   \
              r4.z = fmaxf(acc.z, 0.f); r4.w = fmaxf(acc.w, 0.f);                   \
              *(float4*)&OUT[(size_t)row * 64 + c0] = r4; } }
    EC_STORE(0, acc0) EC_STORE(1, acc1) EC_STORE(2, acc2) EC_STORE(3, acc3)
    #undef EC_STORE
}

// ---------------- GAT GEMM (tiled) + attention scores fused ----------------
// G[N,128] = H @ W ; asrc/adst per node per head from in-register tile.
__global__ __launch_bounds__(TPB) void k_gemm_gat(const float* __restrict__ H, const float* __restrict__ W,
                                                  const float* __restrict__ att_src, const float* __restrict__ att_dst,
                                                  float* __restrict__ G, float* __restrict__ asrc,
                                                  float* __restrict__ adst, int n) {
    __shared__ float Alds[64 * 68];
    __shared__ float Wlds[64 * 132];
    const int t = threadIdx.x;
    const int base = blockIdx.x * 64;
    // stage A tile
    {
        int r16 = t >> 4, cc = (t & 15) * 4;
        #pragma unroll
        for (int rep = 0; rep < 4; rep++) {
            int r = rep * 16 + r16;
            int row = base + r;
            float4 v = make_float4(0.f, 0.f, 0.f, 0.f);
            if (row < n) v = *(const float4*)&H[(size_t)row * 64 + cc];
            *(float4*)&Alds[r * 68 + cc] = v;
        }
    }
    // stage W [64][128] -> stride 132
    {
        #pragma unroll
        for (int rep = 0; rep < 8; rep++) {
            int idx4 = (rep * 256 + t) * 4;   // 0..8188
            int r = idx4 >> 7, c = idx4 & 127;
            *(float4*)&Wlds[r * 132 + c] = *(const float4*)&W[r * 128 + c];
        }
    }
    __syncthreads();

    const int r0 = (t >> 4) * 4, c0 = (t & 15) * 4;
    float4 p00 = make_float4(0.f, 0.f, 0.f, 0.f), p01 = p00, p02 = p00, p03 = p00;  // head0 rows 0..3
    float4 p10 = p00, p11 = p00, p12 = p00, p13 = p00;                              // head1
    #pragma unroll
    for (int k = 0; k < 64; k += 4) {
        float4 a0 = *(float4*)&Alds[(r0 + 0) * 68 + k];
        float4 a1 = *(float4*)&Alds[(r0 + 1) * 68 + k];
        float4 a2 = *(float4*)&Alds[(r0 + 2) * 68 + k];
        float4 a3 = *(float4*)&Alds[(r0 + 3) * 68 + k];
        float4 u0 = *(float4*)&Wlds[(k + 0) * 132 + c0];
        float4 u1 = *(float4*)&Wlds[(k + 1) * 132 + c0];
        float4 u2 = *(float4*)&Wlds[(k + 2) * 132 + c0];
        float4 u3 = *(float4*)&Wlds[(k + 3) * 132 + c0];
        MAC4(p00, a0, u0, u1, u2, u3);
        MAC4(p01, a1, u0, u1, u2, u3);
        MAC4(p02, a2, u0, u1, u2, u3);
        MAC4(p03, a3, u0, u1, u2, u3);
        float4 v0 = *(float4*)&Wlds[(k + 0) * 132 + 64 + c0];
        float4 v1 = *(float4*)&Wlds[(k + 1) * 132 + 64 + c0];
        float4 v2 = *(float4*)&Wlds[(k + 2) * 132 + 64 + c0];
        float4 v3 = *(float4*)&Wlds[(k + 3) * 132 + 64 + c0];
        MAC4(p10, a0, v0, v1, v2, v3);
        MAC4(p11, a1, v0, v1, v2, v3);
        MAC4(p12, a2, v0, v1, v2, v3);
        MAC4(p13, a3, v0, v1, v2, v3);
    }
    const float4 as0 = *(const float4*)&att_src[c0];
    const float4 as1 = *(const float4*)&att_src[64 + c0];
    const float4 ad0 = *(const float4*)&att_dst[c0];
    const float4 ad1 = *(const float4*)&att_dst[64 + c0];
    #define DOT4(a, b) (a.x * b.x + a.y * b.y + a.z * b.z + a.w * b.w)
    #define GAT_ROW(i, h0, h1)                                                      \
        { int row = base + r0 + i;                                                  \
          float s0 = DOT4(h0, as0), s1 = DOT4(h1, as1);                             \
          float d0 = DOT4(h0, ad0), d1 = DOT4(h1, ad1);                             \
          s0 += __shfl_xor(s0, 1); s1 += __shfl_xor(s1, 1);                         \
          d0 += __shfl_xor(d0, 1); d1 += __shfl_xor(d1, 1);                         \
          s0 += __shfl_xor(s0, 2); s1 += __shfl_xor(s1, 2);                         \
          d0 += __shfl_xor(d0, 2); d1 += __shfl_xor(d1, 2);                         \
          s0 += __shfl_xor(s0, 4); s1 += __shfl_xor(s1, 4);                         \
          d0 += __shfl_xor(d0, 4); d1 += __shfl_xor(d1, 4);                         \
          s0 += __shfl_xor(s0, 8); s1 += __shfl_xor(s1, 8);                         \
          d0 += __shfl_xor(d0, 8); d1 += __shfl_xor(d1, 8);                         \
          if (row < n) {                                                            \
              *(float4*)&G[(size_t)row * 128 + c0] = h0;                            \
              *(float4*)&G[(size_t)row * 128 + 64 + c0] = h1;                       \
              if ((t & 15) == 0) {                                                  \
                  float2 sv; sv.x = s0; sv.y = s1;                                  \
                  float2 dv; dv.x = d0; dv.y = d1;                                  \
                  *(float2*)&asrc[(size_t)row * 2] = sv;                            \
                  *(float2*)&adst[(size_t)row * 2] = dv; } } }
    GAT_ROW(0, p00, p10) GAT_ROW(1, p01, p11) GAT_ROW(2, p02, p12) GAT_ROW(3, p03, p13)
    #undef GAT_ROW
    #undef DOT4
}

// ---------------- GAT aggregation: online segment softmax + weighted sum ----
__global__ __launch_bounds__(TPB) void k_gat_agg(const float* __restrict__ G, const int* __restrict__ row_start,
                                                 const int* __restrict__ csr_src, const float* __restrict__ asrc,
                                                 const float* __restrict__ adst, const float* __restrict__ bgat,
                                                 float* __restrict__ OUT, int n) {
    int wave = threadIdx.x >> 6, lane = threadIdx.x & 63;
    int g = lane >> 4;
    int c4 = (lane & 15) * 4;
    for (int node = blockIdx.x * 4 + wave; node < n; node += gridDim.x * 4) {
        int beg = row_start[node], end = row_start[node + 1];
        float2 adv = *reinterpret_cast<const float2*>(&adst[(size_t)node * 2]);
        float m0 = -INFINITY, m1 = -INFINITY, d0 = 0.f, d1 = 0.f;
        float A0x = 0.f, A0y = 0.f, A0z = 0.f, A0w = 0.f;
        float A1x = 0.f, A1y = 0.f, A1z = 0.f, A1w = 0.f;
        for (int chunk = beg; chunk < end; chunk += 64) {
            int cdeg = min(end - chunk, 64);
            bool valid = (lane < cdeg);
            int s_l = valid ? csr_src[chunk + lane] : 0;
            float al0 = -INFINITY, al1 = -INFINITY;
            if (valid) {
                float2 av = *reinterpret_cast<const float2*>(&asrc[(size_t)s_l * 2]);
                float t0 = av.x + adv.x, t1 = av.y + adv.y;
                al0 = (t0 > 0.f) ? t0 : 0.2f * t0;
                al1 = (t1 > 0.f) ? t1 : 0.2f * t1;
            }
            float cm0 = al0, cm1 = al1;
            #pragma unroll
            for (int off = 1; off < 64; off <<= 1) {
                cm0 = fmaxf(cm0, __shfl_xor(cm0, off));
                cm1 = fmaxf(cm1, __shfl_xor(cm1, off));
            }
            float nm0 = fmaxf(m0, cm0), nm1 = fmaxf(m1, cm1);
            float sc0 = __expf(m0 - nm0), sc1 = __expf(m1 - nm1);  // 0 on first chunk
            float w0 = valid ? __expf(al0 - nm0) : 0.f;
            float w1 = valid ? __expf(al1 - nm1) : 0.f;
            float cd0 = w0, cd1 = w1;
            #pragma unroll
            for (int off = 1; off < 64; off <<= 1) {
                cd0 += __shfl_xor(cd0, off);
                cd1 += __shfl_xor(cd1, off);
            }
            d0 = d0 * sc0 + cd0;
            d1 = d1 * sc1 + cd1;
            A0x *= sc0; A0y *= sc0; A0z *= sc0; A0w *= sc0;
            A1x *= sc1; A1y *= sc1; A1z *= sc1; A1w *= sc1;
            m0 = nm0; m1 = nm1;
            int iters = (cdeg + 3) >> 2;
            for (int it = 0; it < iters; it++) {
                int el = g + 4 * it;
                int se = __shfl(s_l, el);
                float w0e = __shfl(w0, el);
                float w1e = __shfl(w1, el);
                if (el < cdeg) {
                    const float4 g0 = *reinterpret_cast<const float4*>(&G[(size_t)se * 128 + c4]);
                    const float4 g1 = *reinterpret_cast<const float4*>(&G[(size_t)se * 128 + 64 + c4]);
                    A0x = fmaf(w0e, g0.x, A0x); A0y = fmaf(w0e, g0.y, A0y);
                    A0z = fmaf(w0e, g0.z, A0z); A0w = fmaf(w0e, g0.w, A0w);
                    A1x = fmaf(w1e, g1.x, A1x); A1y = fmaf(w1e, g1.y, A1y);
                    A1z = fmaf(w1e, g1.z, A1z); A1w = fmaf(w1e, g1.w, A1w);
                }
            }
        }
        #pragma unroll
        for (int off = 16; off < 64; off <<= 1) {
            A0x += __shfl_xor(A0x, off); A0y += __shfl_xor(A0y, off);
            A0z += __shfl_xor(A0z, off); A0w += __shfl_xor(A0w, off);
            A1x += __shfl_xor(A1x, off); A1y += __shfl_xor(A1y, off);
            A1z += __shfl_xor(A1z, off); A1w += __shfl_xor(A1w, off);
        }
        if (g == 0) {
            const float4 bg = *reinterpret_cast<const float4*>(&bgat[c4]);
            float r0 = 1.f / (d0 + 1e-16f), r1 = 1.f / (d1 + 1e-16f);
            float4 r;
            r.x = 0.5f * (A0x * r0 + A1x * r1) + bg.x;
            r.y = 0.5f * (A0y * r0 + A1y * r1) + bg.y;
            r.z = 0.5f * (A0z * r0 + A1z * r1) + bg.z;
            r.w = 0.5f * (A0w * r0 + A1w * r1) + bg.w;
            *reinterpret_cast<float4*>(&OUT[(size_t)node * 64 + c4]) = r;
        }
    }
}

extern "C" void kernel_launch(void* const* d_in, const int* in_sizes, int n_in,
                              void* d_out, int out_size, void* d_ws, size_t ws_size,
                              hipStream_t stream) {
    const float* x   = (const float*)d_in[0];
    const int*   ei  = (const int*)d_in[1];
    const float* ea  = (const float*)d_in[2];
    const int N = in_sizes[0] / 64;
    const int E = in_sizes[1] / 2;
    const int* src = ei;
    const int* dst = ei + E;

    const float* wn[3] = {(const float*)d_in[3],  (const float*)d_in[9],  (const float*)d_in[15]};
    const float* bn[3] = {(const float*)d_in[4],  (const float*)d_in[10], (const float*)d_in[16]};
    const float* we[3] = {(const float*)d_in[5],  (const float*)d_in[11], (const float*)d_in[17]};
    const float* be[3] = {(const float*)d_in[6],  (const float*)d_in[12], (const float*)d_in[18]};
    const float* wc[3] = {(const float*)d_in[7],  (const float*)d_in[13], (const float*)d_in[19]};
    const float* bc[3] = {(const float*)d_in[8],  (const float*)d_in[14], (const float*)d_in[20]};
    const float* wgat    = (const float*)d_in[21];
    const float* att_src = (const float*)d_in[22];
    const float* att_dst = (const float*)d_in[23];
    const float* bgat    = (const float*)d_in[24];

    // workspace carve-up (256B aligned)
    char* ws = (char*)d_ws;
    size_t off = 0;
    auto alloc = [&](size_t bytes) -> void* {
        void* p = ws + off;
        off = (off + bytes + 255) & ~(size_t)255;
        return p;
    };
    int*   row_start = (int*)alloc((size_t)(N + 1) * 4);
    int*   cursor    = (int*)alloc((size_t)N * 4);
    int*   partials  = (int*)alloc(1024 * 4);
    int*   csr_e     = (int*)alloc((size_t)E * 4);
    int*   csr_src   = (int*)alloc((size_t)E * 4);
    float* Wc        = (float*)alloc((size_t)3 * 4480 * 4);   // per layer: W1(4096) W2(320) cv(64)
    float* B5        = (float*)alloc((size_t)N * 5 * 4);
    float* bufH      = (float*)alloc((size_t)N * 64 * 4);     // layer-3 output (GAT input)
    float* bufG      = (float*)alloc((size_t)N * 128 * 4);    // L0/L1 ping-pong halves; later G
    float* asrc      = (float*)alloc((size_t)N * 2 * 4);
    float* adst      = (float*)alloc((size_t)N * 2 * 4);
    float* h0 = bufG;                     // [N,64] alias (dead before G written)
    float* h1 = bufG + (size_t)N * 64;    // [N,64] alias
    float* out = (float*)d_out;

    const int nbN = (N + TPB - 1) / TPB;
    const int nbE = (E + TPB - 1) / TPB;
    const int nodeBlocks = (N + 3) / 4;
    const int tiles = (N + 63) / 64;

    // ---- fold weights ----
    for (int l = 0; l < 3; l++) {
        float* W1 = Wc + l * 4480;
        k_combine<<<1, TPB, 0, stream>>>(wn[l], bn[l], we[l], be[l], wc[l], bc[l],
                                         W1, W1 + 4096, W1 + 4416);
    }

    // ---- build CSR by dst ----
    hipMemsetAsync(row_start, 0, (size_t)N * 4, stream);
    k_hist<<<nbE, TPB, 0, stream>>>(dst, row_start, E);
    k_scan1<<<nbN, TPB, 0, stream>>>(row_start, partials, N);
    k_scan2<<<1, 1024, 0, stream>>>(partials, nbN);
    k_scan3<<<nbN, TPB, 0, stream>>>(row_start, partials, cursor, N, E);
    k_scatter<<<nbE, TPB, 0, stream>>>(src, dst, cursor, csr_e, csr_src, E);

    // ---- one-time edge-attr aggregation ----
    k_aggB5<<<nodeBlocks, TPB, 0, stream>>>(row_start, csr_e, ea, B5, N);

    // ---- 3 fused edge-conv layers (gather + GEMM) ----
    k_ec_layer<<<tiles, TPB, 0, stream>>>(x,  row_start, csr_src, B5, Wc,            h0,   N);
    k_ec_layer<<<tiles, TPB, 0, stream>>>(h0, row_start, csr_src, B5, Wc + 4480,     h1,   N);
    k_ec_layer<<<tiles, TPB, 0, stream>>>(h1, row_start, csr_src, B5, Wc + 2 * 4480, bufH, N);

    // ---- GAT ----
    k_gemm_gat<<<tiles, TPB, 0, stream>>>(bufH, wgat, att_src, att_dst, bufG, asrc, adst, N);
    k_gat_agg<<<nodeBlocks, TPB, 0, stream>>>(bufG, row_start, csr_src, asrc, adst, bgat, out, N);
}

// Round 4
// 599.573 us; speedup vs baseline: 3.1166x; 3.1166x over previous
//
#include <hip/hip_runtime.h>
#include <math.h>

// ---------------------------------------------------------------------------
// GraphNet: 3x EdgeConv (fully linearized) + GAT(2 heads, concat=False)
//
// EdgeConv layer l:
//   out[d] = relu( (Σ_{e→d} h[src_e]) @ W1_l + B5[d] @ W2_l + deg[d]·c_l )
//   W1 = wn@wc_top, W2 = we@wc_bot, c = bn@wc_top + be@wc_bot + bc
//   B5[d] = Σ_{e→d} ea_e  (layer-independent, computed once)
// Gather (k_aggA): 1 node/wave, 4 edges per instr (16 lanes x float4).
// GEMMs: 64-row LDS tiles, 4x4 per-thread micro-tile, K-loop unroll capped
//   at 2 (full unroll spilled to scratch: VGPR=256 + 1.4GB HBM in R3).
// ---------------------------------------------------------------------------

#define TPB 256

// 16 FMAs: acc(4 cols) += sum_j a.comp_j * w_j(4 cols)
#define MAC4(acc, a, w0, w1, w2, w3)                                           \
    acc.x = fmaf(a.x, w0.x, acc.x); acc.y = fmaf(a.x, w0.y, acc.y);            \
    acc.z = fmaf(a.x, w0.z, acc.z); acc.w = fmaf(a.x, w0.w, acc.w);            \
    acc.x = fmaf(a.y, w1.x, acc.x); acc.y = fmaf(a.y, w1.y, acc.y);            \
    acc.z = fmaf(a.y, w1.z, acc.z); acc.w = fmaf(a.y, w1.w, acc.w);            \
    acc.x = fmaf(a.z, w2.x, acc.x); acc.y = fmaf(a.z, w2.y, acc.y);            \
    acc.z = fmaf(a.z, w2.z, acc.z); acc.w = fmaf(a.z, w2.w, acc.w);            \
    acc.x = fmaf(a.w, w3.x, acc.x); acc.y = fmaf(a.w, w3.y, acc.y);            \
    acc.z = fmaf(a.w, w3.z, acc.z); acc.w = fmaf(a.w, w3.w, acc.w);

// ---------------- CSR build ----------------
__global__ __launch_bounds__(TPB) void k_hist(const int* __restrict__ dst, int* __restrict__ deg, int E) {
    int e = blockIdx.x * TPB + threadIdx.x;
    if (e < E) atomicAdd(&deg[dst[e]], 1);
}

__global__ __launch_bounds__(TPB) void k_scan1(int* __restrict__ data, int* __restrict__ partials, int n) {
    __shared__ int s[TPB];
    int i = blockIdx.x * TPB + threadIdx.x;
    int v = (i < n) ? data[i] : 0;
    s[threadIdx.x] = v;
    __syncthreads();
    for (int off = 1; off < TPB; off <<= 1) {
        int t = (threadIdx.x >= off) ? s[threadIdx.x - off] : 0;
        __syncthreads();
        s[threadIdx.x] += t;
        __syncthreads();
    }
    if (i < n) data[i] = s[threadIdx.x] - v;  // exclusive
    if (threadIdx.x == TPB - 1) partials[blockIdx.x] = s[TPB - 1];
}

__global__ __launch_bounds__(1024) void k_scan2(int* __restrict__ partials, int nb) {
    __shared__ int s[1024];
    int v = (threadIdx.x < nb) ? partials[threadIdx.x] : 0;
    s[threadIdx.x] = v;
    __syncthreads();
    for (int off = 1; off < 1024; off <<= 1) {
        int t = (threadIdx.x >= off) ? s[threadIdx.x - off] : 0;
        __syncthreads();
        s[threadIdx.x] += t;
        __syncthreads();
    }
    if (threadIdx.x < nb) partials[threadIdx.x] = s[threadIdx.x] - v;  // exclusive
}

__global__ __launch_bounds__(TPB) void k_scan3(int* __restrict__ data, const int* __restrict__ partials,
                                               int* __restrict__ cursor, int n, int total) {
    int i = blockIdx.x * TPB + threadIdx.x;
    if (i < n) {
        int v = data[i] + partials[blockIdx.x];
        data[i] = v;
        cursor[i] = v;
    }
    if (i == 0) data[n] = total;
}

__global__ __launch_bounds__(TPB) void k_scatter(const int* __restrict__ src, const int* __restrict__ dst,
                                                 int* __restrict__ cursor, int* __restrict__ csr_e,
                                                 int* __restrict__ csr_src, int E) {
    int e = blockIdx.x * TPB + threadIdx.x;
    if (e < E) {
        int d = dst[e];
        int idx = atomicAdd(&cursor[d], 1);
        csr_e[idx] = e;
        csr_src[idx] = src[e];
    }
}

// ---------------- weight folding (per layer, 1 block) ----------------
__global__ __launch_bounds__(TPB) void k_combine(const float* __restrict__ wn, const float* __restrict__ bn,
                                                 const float* __restrict__ we, const float* __restrict__ be,
                                                 const float* __restrict__ wc, const float* __restrict__ bc,
                                                 float* __restrict__ W1, float* __restrict__ W2,
                                                 float* __restrict__ cv) {
    int tid = threadIdx.x;
    for (int idx = tid; idx < 64 * 64; idx += TPB) {
        int i = idx >> 6, j = idx & 63;
        float acc = 0.f;
        #pragma unroll 8
        for (int k = 0; k < 64; k++) acc = fmaf(wn[i * 64 + k], wc[k * 64 + j], acc);
        W1[idx] = acc;
    }
    for (int idx = tid; idx < 5 * 64; idx += TPB) {
        int i = idx >> 6, j = idx & 63;
        float acc = 0.f;
        #pragma unroll 8
        for (int k = 0; k < 64; k++) acc = fmaf(we[i * 64 + k], wc[(64 + k) * 64 + j], acc);
        W2[idx] = acc;
    }
    for (int j = tid; j < 64; j += TPB) {
        float acc = bc[j];
        for (int k = 0; k < 64; k++) {
            acc = fmaf(bn[k], wc[k * 64 + j], acc);
            acc = fmaf(be[k], wc[(64 + k) * 64 + j], acc);
        }
        cv[j] = acc;
    }
}

// ---------------- B5[d] = sum of ea over incoming edges (once) ----------------
__global__ __launch_bounds__(TPB) void k_aggB5(const int* __restrict__ row_start, const int* __restrict__ csr_e,
                                               const float* __restrict__ EA, float* __restrict__ B5, int n) {
    int wave = threadIdx.x >> 6, lane = threadIdx.x & 63;
    for (int node = blockIdx.x * 4 + wave; node < n; node += gridDim.x * 4) {
        int beg = row_start[node], end = row_start[node + 1];
        float b0 = 0.f, b1 = 0.f, b2 = 0.f, b3 = 0.f, b4 = 0.f;
        for (int chunk = beg; chunk < end; chunk += 64) {
            int j = chunk + lane;
            if (j < end) {
                int e = csr_e[j];
                const float* eap = EA + (size_t)e * 5;
                b0 += eap[0]; b1 += eap[1]; b2 += eap[2]; b3 += eap[3]; b4 += eap[4];
            }
        }
        #pragma unroll
        for (int off = 1; off < 64; off <<= 1) {
            b0 += __shfl_xor(b0, off);
            b1 += __shfl_xor(b1, off);
            b2 += __shfl_xor(b2, off);
            b3 += __shfl_xor(b3, off);
            b4 += __shfl_xor(b4, off);
        }
        if (lane == 0) {
            float* bp = B5 + (size_t)node * 5;
            bp[0] = b0; bp[1] = b1; bp[2] = b2; bp[3] = b3; bp[4] = b4;
        }
    }
}

// ---------------- A[d] = sum of H[src_e] (pure gather-sum, 4 edges/instr) ----
__global__ __launch_bounds__(TPB) void k_aggA(const float* __restrict__ H, const int* __restrict__ row_start,
                                              const int* __restrict__ csr_src, float* __restrict__ OUT, int n) {
    int wave = threadIdx.x >> 6, lane = threadIdx.x & 63;
    int g = lane >> 4;            // edge subgroup 0..3
    int c4 = (lane & 15) * 4;     // column base
    for (int node = blockIdx.x * 4 + wave; node < n; node += gridDim.x * 4) {
        int beg = row_start[node], end = row_start[node + 1];
        float ax = 0.f, ay = 0.f, az = 0.f, aw = 0.f;
        for (int chunk = beg; chunk < end; chunk += 64) {
            int cdeg = min(end - chunk, 64);
            int s_l = (chunk + lane < end) ? csr_src[chunk + lane] : 0;
            int iters = (cdeg + 3) >> 2;
            for (int it = 0; it < iters; it++) {
                int el = g + 4 * it;
                int se = __shfl(s_l, el);
                if (el < cdeg) {
                    const float4 v = *reinterpret_cast<const float4*>(&H[(size_t)se * 64 + c4]);
                    ax += v.x; ay += v.y; az += v.z; aw += v.w;
                }
            }
        }
        ax += __shfl_xor(ax, 16); ay += __shfl_xor(ay, 16); az += __shfl_xor(az, 16); aw += __shfl_xor(aw, 16);
        ax += __shfl_xor(ax, 32); ay += __shfl_xor(ay, 32); az += __shfl_xor(az, 32); aw += __shfl_xor(aw, 32);
        if (g == 0) {
            float4 r; r.x = ax; r.y = ay; r.z = az; r.w = aw;
            *reinterpret_cast<float4*>(&OUT[(size_t)node * 64 + c4]) = r;
        }
    }
}

// ---------------- tiled EdgeConv GEMM: out = relu(A@W1 + B5@W2 + deg*c) -----
// 64-row tile, 4x4 micro-tile, K=64, unroll capped at 2 (spill guard).
__global__ __launch_bounds__(TPB) void k_gemm_ec_t(const float* __restrict__ A,
                                                   const float* __restrict__ Wfold,  // W1(4096)|W2(320)|cv(64)
                                                   const float* __restrict__ B5,
                                                   const int* __restrict__ row_start,
                                                   float* __restrict__ OUT, int n) {
    __shared__ float Alds[64 * 68];
    __shared__ float Wlds[64 * 68];
    const int t = threadIdx.x;
    const int base = blockIdx.x * 64;
    {
        int r16 = t >> 4, cc = (t & 15) * 4;
        #pragma unroll
        for (int rep = 0; rep < 4; rep++) {
            int r = rep * 16 + r16;
            int row = base + r;
            float4 v = make_float4(0.f, 0.f, 0.f, 0.f);
            if (row < n) v = *(const float4*)&A[(size_t)row * 64 + cc];
            *(float4*)&Alds[r * 68 + cc] = v;
            *(float4*)&Wlds[r * 68 + cc] = *(const float4*)&Wfold[r * 64 + cc];
        }
    }
    __syncthreads();

    const int r0 = (t >> 4) * 4, c0 = (t & 15) * 4;
    float4 acc0 = make_float4(0.f, 0.f, 0.f, 0.f), acc1 = acc0, acc2 = acc0, acc3 = acc0;
    #pragma unroll 2
    for (int k = 0; k < 64; k += 4) {
        float4 a0 = *(float4*)&Alds[(r0 + 0) * 68 + k];
        float4 a1 = *(float4*)&Alds[(r0 + 1) * 68 + k];
        float4 a2 = *(float4*)&Alds[(r0 + 2) * 68 + k];
        float4 a3 = *(float4*)&Alds[(r0 + 3) * 68 + k];
        float4 w0 = *(float4*)&Wlds[(k + 0) * 68 + c0];
        float4 w1 = *(float4*)&Wlds[(k + 1) * 68 + c0];
        float4 w2 = *(float4*)&Wlds[(k + 2) * 68 + c0];
        float4 w3 = *(float4*)&Wlds[(k + 3) * 68 + c0];
        MAC4(acc0, a0, w0, w1, w2, w3);
        MAC4(acc1, a1, w0, w1, w2, w3);
        MAC4(acc2, a2, w0, w1, w2, w3);
        MAC4(acc3, a3, w0, w1, w2, w3);
    }
    // epilogue: + B5@W2 + deg*cv, relu
    float4 w2c[5];
    #pragma unroll
    for (int j = 0; j < 5; j++) w2c[j] = *(const float4*)&Wfold[4096 + j * 64 + c0];
    const float4 cv4 = *(const float4*)&Wfold[4416 + c0];
    #define EC_STORE(i, acc)                                                        \
        { int row = base + r0 + i;                                                  \
          if (row < n) {                                                            \
              const float* bp = B5 + (size_t)row * 5;                               \
              float deg = (float)(row_start[row + 1] - row_start[row]);             \
              float4 q;                                                             \
              q.x = deg * cv4.x; q.y = deg * cv4.y;                                 \
              q.z = deg * cv4.z; q.w = deg * cv4.w;                                 \
              for (int j = 0; j < 5; j++) {                                         \
                  float b = bp[j];                                                  \
                  q.x = fmaf(b, w2c[j].x, q.x); q.y = fmaf(b, w2c[j].y, q.y);       \
                  q.z = fmaf(b, w2c[j].z, q.z); q.w = fmaf(b, w2c[j].w, q.w);       \
              }                                                                     \
              float4 r4;                                                            \
              r4.x = fmaxf(acc.x + q.x, 0.f); r4.y = fmaxf(acc.y + q.y, 0.f);       \
              r4.z = fmaxf(acc.z + q.z, 0.f); r4.w = fmaxf(acc.w + q.w, 0.f);       \
              *(float4*)&OUT[(size_t)row * 64 + c0] = r4; } }
    EC_STORE(0, acc0) EC_STORE(1, acc1) EC_STORE(2, acc2) EC_STORE(3, acc3)
    #undef EC_STORE
}

// ---------------- GAT GEMM (tiled, unroll-capped) + attention scores --------
__global__ __launch_bounds__(TPB) void k_gemm_gat(const float* __restrict__ H, const float* __restrict__ W,
                                                  const float* __restrict__ att_src, const float* __restrict__ att_dst,
                                                  float* __restrict__ G, float* __restrict__ asrc,
                                                  float* __restrict__ adst, int n) {
    __shared__ float Alds[64 * 68];
    __shared__ float Wlds[64 * 132];
    const int t = threadIdx.x;
    const int base = blockIdx.x * 64;
    {
        int r16 = t >> 4, cc = (t & 15) * 4;
        #pragma unroll
        for (int rep = 0; rep < 4; rep++) {
            int r = rep * 16 + r16;
            int row = base + r;
            float4 v = make_float4(0.f, 0.f, 0.f, 0.f);
            if (row < n) v = *(const float4*)&H[(size_t)row * 64 + cc];
            *(float4*)&Alds[r * 68 + cc] = v;
        }
        #pragma unroll
        for (int rep = 0; rep < 8; rep++) {
            int idx4 = (rep * 256 + t) * 4;   // 0..8188
            int r = idx4 >> 7, c = idx4 & 127;
            *(float4*)&Wlds[r * 132 + c] = *(const float4*)&W[r * 128 + c];
        }
    }
    __syncthreads();

    const int r0 = (t >> 4) * 4, c0 = (t & 15) * 4;
    float4 p00 = make_float4(0.f, 0.f, 0.f, 0.f), p01 = p00, p02 = p00, p03 = p00;  // head0
    float4 p10 = p00, p11 = p00, p12 = p00, p13 = p00;                              // head1
    #pragma unroll 2
    for (int k = 0; k < 64; k += 4) {
        float4 a0 = *(float4*)&Alds[(r0 + 0) * 68 + k];
        float4 a1 = *(float4*)&Alds[(r0 + 1) * 68 + k];
        float4 a2 = *(float4*)&Alds[(r0 + 2) * 68 + k];
        float4 a3 = *(float4*)&Alds[(r0 + 3) * 68 + k];
        float4 u0 = *(float4*)&Wlds[(k + 0) * 132 + c0];
        float4 u1 = *(float4*)&Wlds[(k + 1) * 132 + c0];
        float4 u2 = *(float4*)&Wlds[(k + 2) * 132 + c0];
        float4 u3 = *(float4*)&Wlds[(k + 3) * 132 + c0];
        MAC4(p00, a0, u0, u1, u2, u3);
        MAC4(p01, a1, u0, u1, u2, u3);
        MAC4(p02, a2, u0, u1, u2, u3);
        MAC4(p03, a3, u0, u1, u2, u3);
        float4 v0 = *(float4*)&Wlds[(k + 0) * 132 + 64 + c0];
        float4 v1 = *(float4*)&Wlds[(k + 1) * 132 + 64 + c0];
        float4 v2 = *(float4*)&Wlds[(k + 2) * 132 + 64 + c0];
        float4 v3 = *(float4*)&Wlds[(k + 3) * 132 + 64 + c0];
        MAC4(p10, a0, v0, v1, v2, v3);
        MAC4(p11, a1, v0, v1, v2, v3);
        MAC4(p12, a2, v0, v1, v2, v3);
        MAC4(p13, a3, v0, v1, v2, v3);
    }
    const float4 as0 = *(const float4*)&att_src[c0];
    const float4 as1 = *(const float4*)&att_src[64 + c0];
    const float4 ad0 = *(const float4*)&att_dst[c0];
    const float4 ad1 = *(const float4*)&att_dst[64 + c0];
    #define DOT4(a, b) (a.x * b.x + a.y * b.y + a.z * b.z + a.w * b.w)
    #define GAT_ROW(i, h0, h1)                                                      \
        { int row = base + r0 + i;                                                  \
          float s0 = DOT4(h0, as0), s1 = DOT4(h1, as1);                             \
          float d0 = DOT4(h0, ad0), d1 = DOT4(h1, ad1);                             \
          s0 += __shfl_xor(s0, 1); s1 += __shfl_xor(s1, 1);                         \
          d0 += __shfl_xor(d0, 1); d1 += __shfl_xor(d1, 1);                         \
          s0 += __shfl_xor(s0, 2); s1 += __shfl_xor(s1, 2);                         \
          d0 += __shfl_xor(d0, 2); d1 += __shfl_xor(d1, 2);                         \
          s0 += __shfl_xor(s0, 4); s1 += __shfl_xor(s1, 4);                         \
          d0 += __shfl_xor(d0, 4); d1 += __shfl_xor(d1, 4);                         \
          s0 += __shfl_xor(s0, 8); s1 += __shfl_xor(s1, 8);                         \
          d0 += __shfl_xor(d0, 8); d1 += __shfl_xor(d1, 8);                         \
          if (row < n) {                                                            \
              *(float4*)&G[(size_t)row * 128 + c0] = h0;                            \
              *(float4*)&G[(size_t)row * 128 + 64 + c0] = h1;                       \
              if ((t & 15) == 0) {                                                  \
                  float2 sv; sv.x = s0; sv.y = s1;                                  \
                  float2 dv; dv.x = d0; dv.y = d1;                                  \
                  *(float2*)&asrc[(size_t)row * 2] = sv;                            \
                  *(float2*)&adst[(size_t)row * 2] = dv; } } }
    GAT_ROW(0, p00, p10) GAT_ROW(1, p01, p11) GAT_ROW(2, p02, p12) GAT_ROW(3, p03, p13)
    #undef GAT_ROW
    #undef DOT4
}

// ---------------- GAT aggregation: online segment softmax + weighted sum ----
__global__ __launch_bounds__(TPB) void k_gat_agg(const float* __restrict__ G, const int* __restrict__ row_start,
                                                 const int* __restrict__ csr_src, const float* __restrict__ asrc,
                                                 const float* __restrict__ adst, const float* __restrict__ bgat,
                                                 float* __restrict__ OUT, int n) {
    int wave = threadIdx.x >> 6, lane = threadIdx.x & 63;
    int g = lane >> 4;
    int c4 = (lane & 15) * 4;
    for (int node = blockIdx.x * 4 + wave; node < n; node += gridDim.x * 4) {
        int beg = row_start[node], end = row_start[node + 1];
        float2 adv = *reinterpret_cast<const float2*>(&adst[(size_t)node * 2]);
        float m0 = -INFINITY, m1 = -INFINITY, d0 = 0.f, d1 = 0.f;
        float A0x = 0.f, A0y = 0.f, A0z = 0.f, A0w = 0.f;
        float A1x = 0.f, A1y = 0.f, A1z = 0.f, A1w = 0.f;
        for (int chunk = beg; chunk < end; chunk += 64) {
            int cdeg = min(end - chunk, 64);
            bool valid = (lane < cdeg);
            int s_l = valid ? csr_src[chunk + lane] : 0;
            float al0 = -INFINITY, al1 = -INFINITY;
            if (valid) {
                float2 av = *reinterpret_cast<const float2*>(&asrc[(size_t)s_l * 2]);
                float t0 = av.x + adv.x, t1 = av.y + adv.y;
                al0 = (t0 > 0.f) ? t0 : 0.2f * t0;
                al1 = (t1 > 0.f) ? t1 : 0.2f * t1;
            }
            float cm0 = al0, cm1 = al1;
            #pragma unroll
            for (int off = 1; off < 64; off <<= 1) {
                cm0 = fmaxf(cm0, __shfl_xor(cm0, off));
                cm1 = fmaxf(cm1, __shfl_xor(cm1, off));
            }
            float nm0 = fmaxf(m0, cm0), nm1 = fmaxf(m1, cm1);
            float sc0 = __expf(m0 - nm0), sc1 = __expf(m1 - nm1);  // 0 on first chunk
            float w0 = valid ? __expf(al0 - nm0) : 0.f;
            float w1 = valid ? __expf(al1 - nm1) : 0.f;
            float cd0 = w0, cd1 = w1;
            #pragma unroll
            for (int off = 1; off < 64; off <<= 1) {
                cd0 += __shfl_xor(cd0, off);
                cd1 += __shfl_xor(cd1, off);
            }
            d0 = d0 * sc0 + cd0;
            d1 = d1 * sc1 + cd1;
            A0x *= sc0; A0y *= sc0; A0z *= sc0; A0w *= sc0;
            A1x *= sc1; A1y *= sc1; A1z *= sc1; A1w *= sc1;
            m0 = nm0; m1 = nm1;
            int iters = (cdeg + 3) >> 2;
            for (int it = 0; it < iters; it++) {
                int el = g + 4 * it;
                int se = __shfl(s_l, el);
                float w0e = __shfl(w0, el);
                float w1e = __shfl(w1, el);
                if (el < cdeg) {
                    const float4 g0 = *reinterpret_cast<const float4*>(&G[(size_t)se * 128 + c4]);
                    const float4 g1 = *reinterpret_cast<const float4*>(&G[(size_t)se * 128 + 64 + c4]);
                    A0x = fmaf(w0e, g0.x, A0x); A0y = fmaf(w0e, g0.y, A0y);
                    A0z = fmaf(w0e, g0.z, A0z); A0w = fmaf(w0e, g0.w, A0w);
                    A1x = fmaf(w1e, g1.x, A1x); A1y = fmaf(w1e, g1.y, A1y);
                    A1z = fmaf(w1e, g1.z, A1z); A1w = fmaf(w1e, g1.w, A1w);
                }
            }
        }
        #pragma unroll
        for (int off = 16; off < 64; off <<= 1) {
            A0x += __shfl_xor(A0x, off); A0y += __shfl_xor(A0y, off);
            A0z += __shfl_xor(A0z, off); A0w += __shfl_xor(A0w, off);
            A1x += __shfl_xor(A1x, off); A1y += __shfl_xor(A1y, off);
            A1z += __shfl_xor(A1z, off); A1w += __shfl_xor(A1w, off);
        }
        if (g == 0) {
            const float4 bg = *reinterpret_cast<const float4*>(&bgat[c4]);
            float r0 = 1.f / (d0 + 1e-16f), r1 = 1.f / (d1 + 1e-16f);
            float4 r;
            r.x = 0.5f * (A0x * r0 + A1x * r1) + bg.x;
            r.y = 0.5f * (A0y * r0 + A1y * r1) + bg.y;
            r.z = 0.5f * (A0z * r0 + A1z * r1) + bg.z;
            r.w = 0.5f * (A0w * r0 + A1w * r1) + bg.w;
            *reinterpret_cast<float4*>(&OUT[(size_t)node * 64 + c4]) = r;
        }
    }
}

extern "C" void kernel_launch(void* const* d_in, const int* in_sizes, int n_in,
                              void* d_out, int out_size, void* d_ws, size_t ws_size,
                              hipStream_t stream) {
    const float* x   = (const float*)d_in[0];
    const int*   ei  = (const int*)d_in[1];
    const float* ea  = (const float*)d_in[2];
    const int N = in_sizes[0] / 64;
    const int E = in_sizes[1] / 2;
    const int* src = ei;
    const int* dst = ei + E;

    const float* wn[3] = {(const float*)d_in[3],  (const float*)d_in[9],  (const float*)d_in[15]};
    const float* bn[3] = {(const float*)d_in[4],  (const float*)d_in[10], (const float*)d_in[16]};
    const float* we[3] = {(const float*)d_in[5],  (const float*)d_in[11], (const float*)d_in[17]};
    const float* be[3] = {(const float*)d_in[6],  (const float*)d_in[12], (const float*)d_in[18]};
    const float* wc[3] = {(const float*)d_in[7],  (const float*)d_in[13], (const float*)d_in[19]};
    const float* bc[3] = {(const float*)d_in[8],  (const float*)d_in[14], (const float*)d_in[20]};
    const float* wgat    = (const float*)d_in[21];
    const float* att_src = (const float*)d_in[22];
    const float* att_dst = (const float*)d_in[23];
    const float* bgat    = (const float*)d_in[24];

    // workspace carve-up (256B aligned)
    char* ws = (char*)d_ws;
    size_t off = 0;
    auto alloc = [&](size_t bytes) -> void* {
        void* p = ws + off;
        off = (off + bytes + 255) & ~(size_t)255;
        return p;
    };
    int*   row_start = (int*)alloc((size_t)(N + 1) * 4);
    int*   cursor    = (int*)alloc((size_t)N * 4);
    int*   partials  = (int*)alloc(1024 * 4);
    int*   csr_e     = (int*)alloc((size_t)E * 4);
    int*   csr_src   = (int*)alloc((size_t)E * 4);
    float* Wc        = (float*)alloc((size_t)3 * 4480 * 4);   // per layer: W1(4096) W2(320) cv(64)
    float* B5        = (float*)alloc((size_t)N * 5 * 4);
    float* bufH      = (float*)alloc((size_t)N * 64 * 4);     // h ping
    float* bufA      = (float*)alloc((size_t)N * 64 * 4);     // gathered A
    float* bufG      = (float*)alloc((size_t)N * 128 * 4);    // h pong (lower half), later G
    float* asrc      = (float*)alloc((size_t)N * 2 * 4);
    float* adst      = (float*)alloc((size_t)N * 2 * 4);
    float* hPong = bufG;                  // [N,64] alias (dead before G written)
    float* out = (float*)d_out;

    const int nbN = (N + TPB - 1) / TPB;
    const int nbE = (E + TPB - 1) / TPB;
    const int nodeBlocks = (N + 3) / 4;
    const int tiles = (N + 63) / 64;

    // ---- fold weights ----
    for (int l = 0; l < 3; l++) {
        float* W1 = Wc + l * 4480;
        k_combine<<<1, TPB, 0, stream>>>(wn[l], bn[l], we[l], be[l], wc[l], bc[l],
                                         W1, W1 + 4096, W1 + 4416);
    }

    // ---- build CSR by dst ----
    hipMemsetAsync(row_start, 0, (size_t)N * 4, stream);
    k_hist<<<nbE, TPB, 0, stream>>>(dst, row_start, E);
    k_scan1<<<nbN, TPB, 0, stream>>>(row_start, partials, N);
    k_scan2<<<1, 1024, 0, stream>>>(partials, nbN);
    k_scan3<<<nbN, TPB, 0, stream>>>(row_start, partials, cursor, N, E);
    k_scatter<<<nbE, TPB, 0, stream>>>(src, dst, cursor, csr_e, csr_src, E);

    // ---- one-time edge-attr aggregation ----
    k_aggB5<<<nodeBlocks, TPB, 0, stream>>>(row_start, csr_e, ea, B5, N);

    // ---- 3 edge-conv layers: gather then tiled GEMM ----
    const float* h_in = x;
    float* h_out[3] = {bufH, hPong, bufH};
    for (int l = 0; l < 3; l++) {
        k_aggA<<<nodeBlocks, TPB, 0, stream>>>(h_in, row_start, csr_src, bufA, N);
        k_gemm_ec_t<<<tiles, TPB, 0, stream>>>(bufA, Wc + l * 4480, B5, row_start, h_out[l], N);
        h_in = h_out[l];
    }

    // ---- GAT ----
    k_gemm_gat<<<tiles, TPB, 0, stream>>>(bufH, wgat, att_src, att_dst, bufG, asrc, adst, N);
    k_gat_agg<<<nodeBlocks, TPB, 0, stream>>>(bufG, row_start, csr_src, asrc, adst, bgat, out, N);
}

// Round 5
// 579.654 us; speedup vs baseline: 3.2237x; 1.0344x over previous
//
#include <hip/hip_runtime.h>
#include <math.h>

// ---------------------------------------------------------------------------
// GraphNet: 3x EdgeConv (fully linearized) + GAT(2 heads, concat=False)
//
// EdgeConv layer l:
//   out[d] = relu( (Σ_{e→d} h[src_e]) @ W1_l + B5[d] @ W2_l + deg[d]·c_l )
//   W1 = wn@wc_top, W2 = we@wc_bot, c = bn@wc_top + be@wc_bot + bc
//   B5[d] = Σ_{e→d} ea_e  (layer-independent, computed once)
// Gathers: one node per 16-LANE GROUP (avg deg 8), lane owns 4 columns
//   (float4) -> accumulators store directly, no cross-lane reductions.
// GEMMs: 64-row LDS tiles, 4x4 micro-tile, K-unroll capped at 2 (spill guard;
//   full unroll hit VGPR=256 + scratch in R3).
// ---------------------------------------------------------------------------

#define TPB 256

#define MAC4(acc, a, w0, w1, w2, w3)                                           \
    acc.x = fmaf(a.x, w0.x, acc.x); acc.y = fmaf(a.x, w0.y, acc.y);            \
    acc.z = fmaf(a.x, w0.z, acc.z); acc.w = fmaf(a.x, w0.w, acc.w);            \
    acc.x = fmaf(a.y, w1.x, acc.x); acc.y = fmaf(a.y, w1.y, acc.y);            \
    acc.z = fmaf(a.y, w1.z, acc.z); acc.w = fmaf(a.y, w1.w, acc.w);            \
    acc.x = fmaf(a.z, w2.x, acc.x); acc.y = fmaf(a.z, w2.y, acc.y);            \
    acc.z = fmaf(a.z, w2.z, acc.z); acc.w = fmaf(a.z, w2.w, acc.w);            \
    acc.x = fmaf(a.w, w3.x, acc.x); acc.y = fmaf(a.w, w3.y, acc.y);            \
    acc.z = fmaf(a.w, w3.z, acc.z); acc.w = fmaf(a.w, w3.w, acc.w);

// ---------------- CSR build ----------------
__global__ __launch_bounds__(TPB) void k_hist(const int* __restrict__ dst, int* __restrict__ deg, int E) {
    int e = blockIdx.x * TPB + threadIdx.x;
    if (e < E) atomicAdd(&deg[dst[e]], 1);
}

__global__ __launch_bounds__(TPB) void k_scan1(int* __restrict__ data, int* __restrict__ partials, int n) {
    __shared__ int s[TPB];
    int i = blockIdx.x * TPB + threadIdx.x;
    int v = (i < n) ? data[i] : 0;
    s[threadIdx.x] = v;
    __syncthreads();
    for (int off = 1; off < TPB; off <<= 1) {
        int t = (threadIdx.x >= off) ? s[threadIdx.x - off] : 0;
        __syncthreads();
        s[threadIdx.x] += t;
        __syncthreads();
    }
    if (i < n) data[i] = s[threadIdx.x] - v;  // exclusive
    if (threadIdx.x == TPB - 1) partials[blockIdx.x] = s[TPB - 1];
}

__global__ __launch_bounds__(1024) void k_scan2(int* __restrict__ partials, int nb) {
    __shared__ int s[1024];
    int v = (threadIdx.x < nb) ? partials[threadIdx.x] : 0;
    s[threadIdx.x] = v;
    __syncthreads();
    for (int off = 1; off < 1024; off <<= 1) {
        int t = (threadIdx.x >= off) ? s[threadIdx.x - off] : 0;
        __syncthreads();
        s[threadIdx.x] += t;
        __syncthreads();
    }
    if (threadIdx.x < nb) partials[threadIdx.x] = s[threadIdx.x] - v;  // exclusive
}

__global__ __launch_bounds__(TPB) void k_scan3(int* __restrict__ data, const int* __restrict__ partials,
                                               int* __restrict__ cursor, int n, int total) {
    int i = blockIdx.x * TPB + threadIdx.x;
    if (i < n) {
        int v = data[i] + partials[blockIdx.x];
        data[i] = v;
        cursor[i] = v;
    }
    if (i == 0) data[n] = total;
}

__global__ __launch_bounds__(TPB) void k_scatter(const int* __restrict__ src, const int* __restrict__ dst,
                                                 int* __restrict__ cursor, int* __restrict__ csr_e,
                                                 int* __restrict__ csr_src, int E) {
    int e = blockIdx.x * TPB + threadIdx.x;
    if (e < E) {
        int d = dst[e];
        int idx = atomicAdd(&cursor[d], 1);
        csr_e[idx] = e;
        csr_src[idx] = src[e];
    }
}

// ---------------- weight folding ----------------
__global__ __launch_bounds__(TPB) void k_combine(const float* __restrict__ wn, const float* __restrict__ bn,
                                                 const float* __restrict__ we, const float* __restrict__ be,
                                                 const float* __restrict__ wc, const float* __restrict__ bc,
                                                 float* __restrict__ W1, float* __restrict__ W2,
                                                 float* __restrict__ cv) {
    int tid = threadIdx.x;
    for (int idx = tid; idx < 64 * 64; idx += TPB) {
        int i = idx >> 6, j = idx & 63;
        float acc = 0.f;
        #pragma unroll 8
        for (int k = 0; k < 64; k++) acc = fmaf(wn[i * 64 + k], wc[k * 64 + j], acc);
        W1[idx] = acc;
    }
    for (int idx = tid; idx < 5 * 64; idx += TPB) {
        int i = idx >> 6, j = idx & 63;
        float acc = 0.f;
        #pragma unroll 8
        for (int k = 0; k < 64; k++) acc = fmaf(we[i * 64 + k], wc[(64 + k) * 64 + j], acc);
        W2[idx] = acc;
    }
    for (int j = tid; j < 64; j += TPB) {
        float acc = bc[j];
        for (int k = 0; k < 64; k++) {
            acc = fmaf(bn[k], wc[k * 64 + j], acc);
            acc = fmaf(be[k], wc[(64 + k) * 64 + j], acc);
        }
        cv[j] = acc;
    }
}

// ---------------- B5[d] = sum of ea over incoming edges (once) --------------
__global__ __launch_bounds__(TPB) void k_aggB5(const int* __restrict__ row_start, const int* __restrict__ csr_e,
                                               const float* __restrict__ EA, float* __restrict__ B5, int n) {
    int wave = threadIdx.x >> 6, lane = threadIdx.x & 63;
    for (int node = blockIdx.x * 4 + wave; node < n; node += gridDim.x * 4) {
        int beg = row_start[node], end = row_start[node + 1];
        float b0 = 0.f, b1 = 0.f, b2 = 0.f, b3 = 0.f, b4 = 0.f;
        for (int chunk = beg; chunk < end; chunk += 64) {
            int j = chunk + lane;
            if (j < end) {
                int e = csr_e[j];
                const float* eap = EA + (size_t)e * 5;
                b0 += eap[0]; b1 += eap[1]; b2 += eap[2]; b3 += eap[3]; b4 += eap[4];
            }
        }
        #pragma unroll
        for (int off = 1; off < 64; off <<= 1) {
            b0 += __shfl_xor(b0, off);
            b1 += __shfl_xor(b1, off);
            b2 += __shfl_xor(b2, off);
            b3 += __shfl_xor(b3, off);
            b4 += __shfl_xor(b4, off);
        }
        if (lane == 0) {
            float* bp = B5 + (size_t)node * 5;
            bp[0] = b0; bp[1] = b1; bp[2] = b2; bp[3] = b3; bp[4] = b4;
        }
    }
}

// ---------------- A[node] = Σ H[src_e] — one node per 16-lane group ---------
__global__ __launch_bounds__(TPB) void k_aggA(const float* __restrict__ H, const int* __restrict__ row_start,
                                              const int* __restrict__ csr_src, float* __restrict__ OUT, int n) {
    const int node = blockIdx.x * 16 + (threadIdx.x >> 4);
    if (node >= n) return;
    const int lane = threadIdx.x & 63;
    const int lid = lane & 15;
    const int gbase = lane & 48;      // group's base lane within the wave
    const int c4 = lid * 4;
    const int beg = row_start[node], end = row_start[node + 1];
    float4 acc = make_float4(0.f, 0.f, 0.f, 0.f);
    for (int chunk = beg; chunk < end; chunk += 16) {
        int cdeg = min(end - chunk, 16);
        int s_l = (chunk + lid < end) ? csr_src[chunk + lid] : 0;
        int it = 0;
        for (; it + 3 < cdeg; it += 4) {
            int se0 = __shfl(s_l, gbase + it);
            int se1 = __shfl(s_l, gbase + it + 1);
            int se2 = __shfl(s_l, gbase + it + 2);
            int se3 = __shfl(s_l, gbase + it + 3);
            float4 v0 = *(const float4*)&H[(size_t)se0 * 64 + c4];
            float4 v1 = *(const float4*)&H[(size_t)se1 * 64 + c4];
            float4 v2 = *(const float4*)&H[(size_t)se2 * 64 + c4];
            float4 v3 = *(const float4*)&H[(size_t)se3 * 64 + c4];
            acc.x += (v0.x + v1.x) + (v2.x + v3.x);
            acc.y += (v0.y + v1.y) + (v2.y + v3.y);
            acc.z += (v0.z + v1.z) + (v2.z + v3.z);
            acc.w += (v0.w + v1.w) + (v2.w + v3.w);
        }
        for (; it < cdeg; it++) {
            int se = __shfl(s_l, gbase + it);
            float4 v = *(const float4*)&H[(size_t)se * 64 + c4];
            acc.x += v.x; acc.y += v.y; acc.z += v.z; acc.w += v.w;
        }
    }
    *(float4*)&OUT[(size_t)node * 64 + c4] = acc;
}

// ---------------- tiled EdgeConv GEMM: out = relu(A@W1 + B5@W2 + deg*c) -----
__global__ __launch_bounds__(TPB) void k_gemm_ec_t(const float* __restrict__ A,
                                                   const float* __restrict__ Wfold,  // W1|W2|cv
                                                   const float* __restrict__ B5,
                                                   const int* __restrict__ row_start,
                                                   float* __restrict__ OUT, int n) {
    __shared__ float Alds[64 * 68];
    __shared__ float Wlds[64 * 68];
    const int t = threadIdx.x;
    const int base = blockIdx.x * 64;
    {
        int r16 = t >> 4, cc = (t & 15) * 4;
        #pragma unroll
        for (int rep = 0; rep < 4; rep++) {
            int r = rep * 16 + r16;
            int row = base + r;
            float4 v = make_float4(0.f, 0.f, 0.f, 0.f);
            if (row < n) v = *(const float4*)&A[(size_t)row * 64 + cc];
            *(float4*)&Alds[r * 68 + cc] = v;
            *(float4*)&Wlds[r * 68 + cc] = *(const float4*)&Wfold[r * 64 + cc];
        }
    }
    __syncthreads();

    const int r0 = (t >> 4) * 4, c0 = (t & 15) * 4;
    float4 acc0 = make_float4(0.f, 0.f, 0.f, 0.f), acc1 = acc0, acc2 = acc0, acc3 = acc0;
    #pragma unroll 2
    for (int k = 0; k < 64; k += 4) {
        float4 a0 = *(float4*)&Alds[(r0 + 0) * 68 + k];
        float4 a1 = *(float4*)&Alds[(r0 + 1) * 68 + k];
        float4 a2 = *(float4*)&Alds[(r0 + 2) * 68 + k];
        float4 a3 = *(float4*)&Alds[(r0 + 3) * 68 + k];
        float4 w0 = *(float4*)&Wlds[(k + 0) * 68 + c0];
        float4 w1 = *(float4*)&Wlds[(k + 1) * 68 + c0];
        float4 w2 = *(float4*)&Wlds[(k + 2) * 68 + c0];
        float4 w3 = *(float4*)&Wlds[(k + 3) * 68 + c0];
        MAC4(acc0, a0, w0, w1, w2, w3);
        MAC4(acc1, a1, w0, w1, w2, w3);
        MAC4(acc2, a2, w0, w1, w2, w3);
        MAC4(acc3, a3, w0, w1, w2, w3);
    }
    float4 w2c[5];
    #pragma unroll
    for (int j = 0; j < 5; j++) w2c[j] = *(const float4*)&Wfold[4096 + j * 64 + c0];
    const float4 cv4 = *(const float4*)&Wfold[4416 + c0];
    #define EC_STORE(i, acc)                                                        \
        { int row = base + r0 + i;                                                  \
          if (row < n) {                                                            \
              const float* bp = B5 + (size_t)row * 5;                               \
              float deg = (float)(row_start[row + 1] - row_start[row]);             \
              float4 q;                                                             \
              q.x = deg * cv4.x; q.y = deg * cv4.y;                                 \
              q.z = deg * cv4.z; q.w = deg * cv4.w;                                 \
              for (int j = 0; j < 5; j++) {                                         \
                  float b = bp[j];                                                  \
                  q.x = fmaf(b, w2c[j].x, q.x); q.y = fmaf(b, w2c[j].y, q.y);       \
                  q.z = fmaf(b, w2c[j].z, q.z); q.w = fmaf(b, w2c[j].w, q.w);       \
              }                                                                     \
              float4 r4;                                                            \
              r4.x = fmaxf(acc.x + q.x, 0.f); r4.y = fmaxf(acc.y + q.y, 0.f);       \
              r4.z = fmaxf(acc.z + q.z, 0.f); r4.w = fmaxf(acc.w + q.w, 0.f);       \
              *(float4*)&OUT[(size_t)row * 64 + c0] = r4; } }
    EC_STORE(0, acc0) EC_STORE(1, acc1) EC_STORE(2, acc2) EC_STORE(3, acc3)
    #undef EC_STORE
}

// ---------------- GAT GEMM (tiled) + attention scores fused -----------------
__global__ __launch_bounds__(TPB) void k_gemm_gat(const float* __restrict__ H, const float* __restrict__ W,
                                                  const float* __restrict__ att_src, const float* __restrict__ att_dst,
                                                  float* __restrict__ G, float* __restrict__ asrc,
                                                  float* __restrict__ adst, int n) {
    __shared__ float Alds[64 * 68];
    __shared__ float Wlds[64 * 132];
    const int t = threadIdx.x;
    const int base = blockIdx.x * 64;
    {
        int r16 = t >> 4, cc = (t & 15) * 4;
        #pragma unroll
        for (int rep = 0; rep < 4; rep++) {
            int r = rep * 16 + r16;
            int row = base + r;
            float4 v = make_float4(0.f, 0.f, 0.f, 0.f);
            if (row < n) v = *(const float4*)&H[(size_t)row * 64 + cc];
            *(float4*)&Alds[r * 68 + cc] = v;
        }
        #pragma unroll
        for (int rep = 0; rep < 8; rep++) {
            int idx4 = (rep * 256 + t) * 4;
            int r = idx4 >> 7, c = idx4 & 127;
            *(float4*)&Wlds[r * 132 + c] = *(const float4*)&W[r * 128 + c];
        }
    }
    __syncthreads();

    const int r0 = (t >> 4) * 4, c0 = (t & 15) * 4;
    float4 p00 = make_float4(0.f, 0.f, 0.f, 0.f), p01 = p00, p02 = p00, p03 = p00;
    float4 p10 = p00, p11 = p00, p12 = p00, p13 = p00;
    #pragma unroll 2
    for (int k = 0; k < 64; k += 4) {
        float4 a0 = *(float4*)&Alds[(r0 + 0) * 68 + k];
        float4 a1 = *(float4*)&Alds[(r0 + 1) * 68 + k];
        float4 a2 = *(float4*)&Alds[(r0 + 2) * 68 + k];
        float4 a3 = *(float4*)&Alds[(r0 + 3) * 68 + k];
        float4 u0 = *(float4*)&Wlds[(k + 0) * 132 + c0];
        float4 u1 = *(float4*)&Wlds[(k + 1) * 132 + c0];
        float4 u2 = *(float4*)&Wlds[(k + 2) * 132 + c0];
        float4 u3 = *(float4*)&Wlds[(k + 3) * 132 + c0];
        MAC4(p00, a0, u0, u1, u2, u3);
        MAC4(p01, a1, u0, u1, u2, u3);
        MAC4(p02, a2, u0, u1, u2, u3);
        MAC4(p03, a3, u0, u1, u2, u3);
        float4 v0 = *(float4*)&Wlds[(k + 0) * 132 + 64 + c0];
        float4 v1 = *(float4*)&Wlds[(k + 1) * 132 + 64 + c0];
        float4 v2 = *(float4*)&Wlds[(k + 2) * 132 + 64 + c0];
        float4 v3 = *(float4*)&Wlds[(k + 3) * 132 + 64 + c0];
        MAC4(p10, a0, v0, v1, v2, v3);
        MAC4(p11, a1, v0, v1, v2, v3);
        MAC4(p12, a2, v0, v1, v2, v3);
        MAC4(p13, a3, v0, v1, v2, v3);
    }
    const float4 as0 = *(const float4*)&att_src[c0];
    const float4 as1 = *(const float4*)&att_src[64 + c0];
    const float4 ad0 = *(const float4*)&att_dst[c0];
    const float4 ad1 = *(const float4*)&att_dst[64 + c0];
    #define DOT4(a, b) (a.x * b.x + a.y * b.y + a.z * b.z + a.w * b.w)
    #define GAT_ROW(i, h0, h1)                                                      \
        { int row = base + r0 + i;                                                  \
          float s0 = DOT4(h0, as0), s1 = DOT4(h1, as1);                             \
          float d0 = DOT4(h0, ad0), d1 = DOT4(h1, ad1);                             \
          s0 += __shfl_xor(s0, 1); s1 += __shfl_xor(s1, 1);                         \
          d0 += __shfl_xor(d0, 1); d1 += __shfl_xor(d1, 1);                         \
          s0 += __shfl_xor(s0, 2); s1 += __shfl_xor(s1, 2);                         \
          d0 += __shfl_xor(d0, 2); d1 += __shfl_xor(d1, 2);                         \
          s0 += __shfl_xor(s0, 4); s1 += __shfl_xor(s1, 4);                         \
          d0 += __shfl_xor(d0, 4); d1 += __shfl_xor(d1, 4);                         \
          s0 += __shfl_xor(s0, 8); s1 += __shfl_xor(s1, 8);                         \
          d0 += __shfl_xor(d0, 8); d1 += __shfl_xor(d1, 8);                         \
          if (row < n) {                                                            \
              *(float4*)&G[(size_t)row * 128 + c0] = h0;                            \
              *(float4*)&G[(size_t)row * 128 + 64 + c0] = h1;                       \
              if ((t & 15) == 0) {                                                  \
                  float2 sv; sv.x = s0; sv.y = s1;                                  \
                  float2 dv; dv.x = d0; dv.y = d1;                                  \
                  *(float2*)&asrc[(size_t)row * 2] = sv;                            \
                  *(float2*)&adst[(size_t)row * 2] = dv; } } }
    GAT_ROW(0, p00, p10) GAT_ROW(1, p01, p11) GAT_ROW(2, p02, p12) GAT_ROW(3, p03, p13)
    #undef GAT_ROW
    #undef DOT4
}

// ---------------- GAT aggregation — one node per 16-lane group --------------
__global__ __launch_bounds__(TPB) void k_gat_agg(const float* __restrict__ G, const int* __restrict__ row_start,
                                                 const int* __restrict__ csr_src, const float* __restrict__ asrc,
                                                 const float* __restrict__ adst, const float* __restrict__ bgat,
                                                 float* __restrict__ OUT, int n) {
    const int node = blockIdx.x * 16 + (threadIdx.x >> 4);
    if (node >= n) return;
    const int lane = threadIdx.x & 63;
    const int lid = lane & 15;
    const int gbase = lane & 48;
    const int c4 = lid * 4;
    const int beg = row_start[node], end = row_start[node + 1];
    const float2 adv = *(const float2*)&adst[(size_t)node * 2];
    float m0 = -INFINITY, m1 = -INFINITY, d0 = 0.f, d1 = 0.f;
    float4 A0 = make_float4(0.f, 0.f, 0.f, 0.f), A1 = A0;
    for (int chunk = beg; chunk < end; chunk += 16) {
        int cdeg = min(end - chunk, 16);
        bool valid = (lid < cdeg);
        int s_l = valid ? csr_src[chunk + lid] : 0;
        float al0 = -INFINITY, al1 = -INFINITY;
        if (valid) {
            float2 av = *(const float2*)&asrc[(size_t)s_l * 2];
            float t0 = av.x + adv.x, t1 = av.y + adv.y;
            al0 = (t0 > 0.f) ? t0 : 0.2f * t0;
            al1 = (t1 > 0.f) ? t1 : 0.2f * t1;
        }
        float cm0 = al0, cm1 = al1;
        #pragma unroll
        for (int off = 1; off < 16; off <<= 1) {
            cm0 = fmaxf(cm0, __shfl_xor(cm0, off));
            cm1 = fmaxf(cm1, __shfl_xor(cm1, off));
        }
        float nm0 = fmaxf(m0, cm0), nm1 = fmaxf(m1, cm1);
        float sc0 = __expf(m0 - nm0), sc1 = __expf(m1 - nm1);  // 0 on first chunk
        float w0 = valid ? __expf(al0 - nm0) : 0.f;
        float w1 = valid ? __expf(al1 - nm1) : 0.f;
        float cd0 = w0, cd1 = w1;
        #pragma unroll
        for (int off = 1; off < 16; off <<= 1) {
            cd0 += __shfl_xor(cd0, off);
            cd1 += __shfl_xor(cd1, off);
        }
        d0 = d0 * sc0 + cd0;
        d1 = d1 * sc1 + cd1;
        A0.x *= sc0; A0.y *= sc0; A0.z *= sc0; A0.w *= sc0;
        A1.x *= sc1; A1.y *= sc1; A1.z *= sc1; A1.w *= sc1;
        m0 = nm0; m1 = nm1;
        int it = 0;
        for (; it + 1 < cdeg; it += 2) {
            int se0 = __shfl(s_l, gbase + it);
            int se1 = __shfl(s_l, gbase + it + 1);
            float w0a = __shfl(w0, gbase + it), w1a = __shfl(w1, gbase + it);
            float w0b = __shfl(w0, gbase + it + 1), w1b = __shfl(w1, gbase + it + 1);
            float4 ga0 = *(const float4*)&G[(size_t)se0 * 128 + c4];
            float4 ga1 = *(const float4*)&G[(size_t)se0 * 128 + 64 + c4];
            float4 gb0 = *(const float4*)&G[(size_t)se1 * 128 + c4];
            float4 gb1 = *(const float4*)&G[(size_t)se1 * 128 + 64 + c4];
            A0.x = fmaf(w0a, ga0.x, fmaf(w0b, gb0.x, A0.x));
            A0.y = fmaf(w0a, ga0.y, fmaf(w0b, gb0.y, A0.y));
            A0.z = fmaf(w0a, ga0.z, fmaf(w0b, gb0.z, A0.z));
            A0.w = fmaf(w0a, ga0.w, fmaf(w0b, gb0.w, A0.w));
            A1.x = fmaf(w1a, ga1.x, fmaf(w1b, gb1.x, A1.x));
            A1.y = fmaf(w1a, ga1.y, fmaf(w1b, gb1.y, A1.y));
            A1.z = fmaf(w1a, ga1.z, fmaf(w1b, gb1.z, A1.z));
            A1.w = fmaf(w1a, ga1.w, fmaf(w1b, gb1.w, A1.w));
        }
        if (it < cdeg) {
            int se = __shfl(s_l, gbase + it);
            float w0a = __shfl(w0, gbase + it), w1a = __shfl(w1, gbase + it);
            float4 g0 = *(const float4*)&G[(size_t)se * 128 + c4];
            float4 g1 = *(const float4*)&G[(size_t)se * 128 + 64 + c4];
            A0.x = fmaf(w0a, g0.x, A0.x); A0.y = fmaf(w0a, g0.y, A0.y);
            A0.z = fmaf(w0a, g0.z, A0.z); A0.w = fmaf(w0a, g0.w, A0.w);
            A1.x = fmaf(w1a, g1.x, A1.x); A1.y = fmaf(w1a, g1.y, A1.y);
            A1.z = fmaf(w1a, g1.z, A1.z); A1.w = fmaf(w1a, g1.w, A1.w);
        }
    }
    const float4 bg = *(const float4*)&bgat[c4];
    float r0 = 1.f / (d0 + 1e-16f), r1 = 1.f / (d1 + 1e-16f);
    float4 r;
    r.x = 0.5f * (A0.x * r0 + A1.x * r1) + bg.x;
    r.y = 0.5f * (A0.y * r0 + A1.y * r1) + bg.y;
    r.z = 0.5f * (A0.z * r0 + A1.z * r1) + bg.z;
    r.w = 0.5f * (A0.w * r0 + A1.w * r1) + bg.w;
    *(float4*)&OUT[(size_t)node * 64 + c4] = r;
}

extern "C" void kernel_launch(void* const* d_in, const int* in_sizes, int n_in,
                              void* d_out, int out_size, void* d_ws, size_t ws_size,
                              hipStream_t stream) {
    const float* x   = (const float*)d_in[0];
    const int*   ei  = (const int*)d_in[1];
    const float* ea  = (const float*)d_in[2];
    const int N = in_sizes[0] / 64;
    const int E = in_sizes[1] / 2;
    const int* src = ei;
    const int* dst = ei + E;

    const float* wn[3] = {(const float*)d_in[3],  (const float*)d_in[9],  (const float*)d_in[15]};
    const float* bn[3] = {(const float*)d_in[4],  (const float*)d_in[10], (const float*)d_in[16]};
    const float* we[3] = {(const float*)d_in[5],  (const float*)d_in[11], (const float*)d_in[17]};
    const float* be[3] = {(const float*)d_in[6],  (const float*)d_in[12], (const float*)d_in[18]};
    const float* wc[3] = {(const float*)d_in[7],  (const float*)d_in[13], (const float*)d_in[19]};
    const float* bc[3] = {(const float*)d_in[8],  (const float*)d_in[14], (const float*)d_in[20]};
    const float* wgat    = (const float*)d_in[21];
    const float* att_src = (const float*)d_in[22];
    const float* att_dst = (const float*)d_in[23];
    const float* bgat    = (const float*)d_in[24];

    // workspace carve-up (256B aligned)
    char* ws = (char*)d_ws;
    size_t off = 0;
    auto alloc = [&](size_t bytes) -> void* {
        void* p = ws + off;
        off = (off + bytes + 255) & ~(size_t)255;
        return p;
    };
    int*   row_start = (int*)alloc((size_t)(N + 1) * 4);
    int*   cursor    = (int*)alloc((size_t)N * 4);
    int*   partials  = (int*)alloc(1024 * 4);
    int*   csr_e     = (int*)alloc((size_t)E * 4);
    int*   csr_src   = (int*)alloc((size_t)E * 4);
    float* Wc        = (float*)alloc((size_t)3 * 4480 * 4);   // per layer: W1(4096) W2(320) cv(64)
    float* B5        = (float*)alloc((size_t)N * 5 * 4);
    float* bufH      = (float*)alloc((size_t)N * 64 * 4);     // h ping
    float* bufA      = (float*)alloc((size_t)N * 64 * 4);     // gathered A
    float* bufG      = (float*)alloc((size_t)N * 128 * 4);    // h pong (lower half), later G
    float* asrc      = (float*)alloc((size_t)N * 2 * 4);
    float* adst      = (float*)alloc((size_t)N * 2 * 4);
    float* hPong = bufG;                  // [N,64] alias (dead before G written)
    float* out = (float*)d_out;

    const int nbN = (N + TPB - 1) / TPB;
    const int nbE = (E + TPB - 1) / TPB;
    const int nodeBlocks = (N + 3) / 4;
    const int grpBlocks = (N + 15) / 16;   // 16 nodes per 256-thread block
    const int tiles = (N + 63) / 64;

    // ---- fold weights ----
    for (int l = 0; l < 3; l++) {
        float* W1 = Wc + l * 4480;
        k_combine<<<1, TPB, 0, stream>>>(wn[l], bn[l], we[l], be[l], wc[l], bc[l],
                                         W1, W1 + 4096, W1 + 4416);
    }

    // ---- build CSR by dst ----
    hipMemsetAsync(row_start, 0, (size_t)N * 4, stream);
    k_hist<<<nbE, TPB, 0, stream>>>(dst, row_start, E);
    k_scan1<<<nbN, TPB, 0, stream>>>(row_start, partials, N);
    k_scan2<<<1, 1024, 0, stream>>>(partials, nbN);
    k_scan3<<<nbN, TPB, 0, stream>>>(row_start, partials, cursor, N, E);
    k_scatter<<<nbE, TPB, 0, stream>>>(src, dst, cursor, csr_e, csr_src, E);

    // ---- one-time edge-attr aggregation ----
    k_aggB5<<<nodeBlocks, TPB, 0, stream>>>(row_start, csr_e, ea, B5, N);

    // ---- 3 edge-conv layers: gather then tiled GEMM ----
    const float* h_in = x;
    float* h_out[3] = {bufH, hPong, bufH};
    for (int l = 0; l < 3; l++) {
        k_aggA<<<grpBlocks, TPB, 0, stream>>>(h_in, row_start, csr_src, bufA, N);
        k_gemm_ec_t<<<tiles, TPB, 0, stream>>>(bufA, Wc + l * 4480, B5, row_start, h_out[l], N);
        h_in = h_out[l];
    }

    // ---- GAT ----
    k_gemm_gat<<<tiles, TPB, 0, stream>>>(bufH, wgat, att_src, att_dst, bufG, asrc, adst, N);
    k_gat_agg<<<grpBlocks, TPB, 0, stream>>>(bufG, row_start, csr_src, asrc, adst, bgat, out, N);
}

// Round 7
// 540.808 us; speedup vs baseline: 3.4553x; 1.0718x over previous
//
#include <hip/hip_runtime.h>
#include <hip/hip_fp16.h>
#include <math.h>

// ---------------------------------------------------------------------------
// GraphNet: 3x EdgeConv (fully linearized) + GAT(2 heads, concat=False)
//
// out[d] = relu( (Σ_{e→d} h[src_e]) @ W1 + B5[d] @ W2 + deg[d]·c )
//   W1 = wn@wc_top, W2 = we@wc_bot, c = bn@wc_top + be@wc_bot + bc
// Precision policy (R6 post-mortem): h stays FP32 — bf16 h compounded to
//   absmax 12.4 through 3 layers; fp16 h would still be ~3. G stored FP16
//   (one rounding, convex-combination consumer -> adds <=~0.25 absmax).
// EC layer = ONE fused kernel: 16-lane-group gather straight into LDS A-tile,
//   then 64x64 tiled GEMM (4x4 micro-tile, K-unroll capped at 2 — R3 spill).
// ---------------------------------------------------------------------------

#define TPB 256

typedef unsigned int u32;

__device__ inline float2 f16unpack2(u32 u) {
    __half2 h = *reinterpret_cast<__half2*>(&u);
    return __half22float2(h);
}
__device__ inline u32 f16pack2(float lo, float hi) {
    __half2 h = __floats2half2_rn(lo, hi);
    return *reinterpret_cast<u32*>(&h);
}
__device__ inline void fma_f16x8(float* acc, uint4 v, float w) {
    float2 t;
    t = f16unpack2(v.x); acc[0] = fmaf(w, t.x, acc[0]); acc[1] = fmaf(w, t.y, acc[1]);
    t = f16unpack2(v.y); acc[2] = fmaf(w, t.x, acc[2]); acc[3] = fmaf(w, t.y, acc[3]);
    t = f16unpack2(v.z); acc[4] = fmaf(w, t.x, acc[4]); acc[5] = fmaf(w, t.y, acc[5]);
    t = f16unpack2(v.w); acc[6] = fmaf(w, t.x, acc[6]); acc[7] = fmaf(w, t.y, acc[7]);
}

#define MAC4(acc, a, w0, w1, w2, w3)                                           \
    acc.x = fmaf(a.x, w0.x, acc.x); acc.y = fmaf(a.x, w0.y, acc.y);            \
    acc.z = fmaf(a.x, w0.z, acc.z); acc.w = fmaf(a.x, w0.w, acc.w);            \
    acc.x = fmaf(a.y, w1.x, acc.x); acc.y = fmaf(a.y, w1.y, acc.y);            \
    acc.z = fmaf(a.y, w1.z, acc.z); acc.w = fmaf(a.y, w1.w, acc.w);            \
    acc.x = fmaf(a.z, w2.x, acc.x); acc.y = fmaf(a.z, w2.y, acc.y);            \
    acc.z = fmaf(a.z, w2.z, acc.z); acc.w = fmaf(a.z, w2.w, acc.w);            \
    acc.x = fmaf(a.w, w3.x, acc.x); acc.y = fmaf(a.w, w3.y, acc.y);            \
    acc.z = fmaf(a.w, w3.z, acc.z); acc.w = fmaf(a.w, w3.w, acc.w);

// ---------------- CSR build ----------------
__global__ __launch_bounds__(TPB) void k_hist(const int* __restrict__ dst, int* __restrict__ deg, int E) {
    int e = blockIdx.x * TPB + threadIdx.x;
    if (e < E) atomicAdd(&deg[dst[e]], 1);
}

__global__ __launch_bounds__(TPB) void k_scan1(int* __restrict__ data, int* __restrict__ partials, int n) {
    __shared__ int s[TPB];
    int i = blockIdx.x * TPB + threadIdx.x;
    int v = (i < n) ? data[i] : 0;
    s[threadIdx.x] = v;
    __syncthreads();
    for (int off = 1; off < TPB; off <<= 1) {
        int t = (threadIdx.x >= off) ? s[threadIdx.x - off] : 0;
        __syncthreads();
        s[threadIdx.x] += t;
        __syncthreads();
    }
    if (i < n) data[i] = s[threadIdx.x] - v;  // exclusive
    if (threadIdx.x == TPB - 1) partials[blockIdx.x] = s[TPB - 1];
}

__global__ __launch_bounds__(1024) void k_scan2(int* __restrict__ partials, int nb) {
    __shared__ int s[1024];
    int v = (threadIdx.x < nb) ? partials[threadIdx.x] : 0;
    s[threadIdx.x] = v;
    __syncthreads();
    for (int off = 1; off < 1024; off <<= 1) {
        int t = (threadIdx.x >= off) ? s[threadIdx.x - off] : 0;
        __syncthreads();
        s[threadIdx.x] += t;
        __syncthreads();
    }
    if (threadIdx.x < nb) partials[threadIdx.x] = s[threadIdx.x] - v;  // exclusive
}

__global__ __launch_bounds__(TPB) void k_scan3(int* __restrict__ data, const int* __restrict__ partials,
                                               int* __restrict__ cursor, int n, int total) {
    int i = blockIdx.x * TPB + threadIdx.x;
    if (i < n) {
        int v = data[i] + partials[blockIdx.x];
        data[i] = v;
        cursor[i] = v;
    }
    if (i == 0) data[n] = total;
}

__global__ __launch_bounds__(TPB) void k_scatter(const int* __restrict__ src, const int* __restrict__ dst,
                                                 int* __restrict__ cursor, int* __restrict__ csr_e,
                                                 int* __restrict__ csr_src, int E) {
    int e = blockIdx.x * TPB + threadIdx.x;
    if (e < E) {
        int d = dst[e];
        int idx = atomicAdd(&cursor[d], 1);
        csr_e[idx] = e;
        csr_src[idx] = src[e];
    }
}

// ---------------- weight folding ----------------
__global__ __launch_bounds__(TPB) void k_combine(const float* __restrict__ wn, const float* __restrict__ bn,
                                                 const float* __restrict__ we, const float* __restrict__ be,
                                                 const float* __restrict__ wc, const float* __restrict__ bc,
                                                 float* __restrict__ W1, float* __restrict__ W2,
                                                 float* __restrict__ cv) {
    int tid = threadIdx.x;
    for (int idx = tid; idx < 64 * 64; idx += TPB) {
        int i = idx >> 6, j = idx & 63;
        float acc = 0.f;
        #pragma unroll 8
        for (int k = 0; k < 64; k++) acc = fmaf(wn[i * 64 + k], wc[k * 64 + j], acc);
        W1[idx] = acc;
    }
    for (int idx = tid; idx < 5 * 64; idx += TPB) {
        int i = idx >> 6, j = idx & 63;
        float acc = 0.f;
        #pragma unroll 8
        for (int k = 0; k < 64; k++) acc = fmaf(we[i * 64 + k], wc[(64 + k) * 64 + j], acc);
        W2[idx] = acc;
    }
    for (int j = tid; j < 64; j += TPB) {
        float acc = bc[j];
        for (int k = 0; k < 64; k++) {
            acc = fmaf(bn[k], wc[k * 64 + j], acc);
            acc = fmaf(be[k], wc[(64 + k) * 64 + j], acc);
        }
        cv[j] = acc;
    }
}

// ---------------- B5[d] = sum of ea over incoming edges (once) --------------
__global__ __launch_bounds__(TPB) void k_aggB5(const int* __restrict__ row_start, const int* __restrict__ csr_e,
                                               const float* __restrict__ EA, float* __restrict__ B5, int n) {
    int wave = threadIdx.x >> 6, lane = threadIdx.x & 63;
    for (int node = blockIdx.x * 4 + wave; node < n; node += gridDim.x * 4) {
        int beg = row_start[node], end = row_start[node + 1];
        float b0 = 0.f, b1 = 0.f, b2 = 0.f, b3 = 0.f, b4 = 0.f;
        for (int chunk = beg; chunk < end; chunk += 64) {
            int j = chunk + lane;
            if (j < end) {
                int e = csr_e[j];
                const float* eap = EA + (size_t)e * 5;
                b0 += eap[0]; b1 += eap[1]; b2 += eap[2]; b3 += eap[3]; b4 += eap[4];
            }
        }
        #pragma unroll
        for (int off = 1; off < 64; off <<= 1) {
            b0 += __shfl_xor(b0, off);
            b1 += __shfl_xor(b1, off);
            b2 += __shfl_xor(b2, off);
            b3 += __shfl_xor(b3, off);
            b4 += __shfl_xor(b4, off);
        }
        if (lane == 0) {
            float* bp = B5 + (size_t)node * 5;
            bp[0] = b0; bp[1] = b1; bp[2] = b2; bp[3] = b3; bp[4] = b4;
        }
    }
}

// ---- fused EC layer: group-gather into LDS A-tile, then tiled GEMM ---------
// block = 64-node tile; 16 lane-groups x 4 serial rows each.
__global__ __launch_bounds__(TPB) void k_ec_fused(const float* __restrict__ H,
                                                  const int* __restrict__ row_start,
                                                  const int* __restrict__ csr_src,
                                                  const float* __restrict__ Wfold,  // W1(4096)|W2(320)|cv(64)
                                                  const float* __restrict__ B5,
                                                  float* __restrict__ OUT, int n) {
    __shared__ float Alds[64 * 68];
    __shared__ float Wlds[64 * 68];
    const int t = threadIdx.x;
    const int base = blockIdx.x * 64;

    // stage W
    {
        int r16 = t >> 4, cc = (t & 15) * 4;
        #pragma unroll
        for (int rep = 0; rep < 4; rep++) {
            int r = rep * 16 + r16;
            *(float4*)&Wlds[r * 68 + cc] = *(const float4*)&Wfold[r * 64 + cc];
        }
    }

    // gather phase
    const int lane = t & 63;
    const int lid = lane & 15;
    const int gbase = lane & 48;
    const int gid = t >> 4;          // group 0..15
    const int c4 = lid * 4;
    for (int i = 0; i < 4; i++) {
        int r = gid * 4 + i;
        int node = base + r;
        float4 acc = make_float4(0.f, 0.f, 0.f, 0.f);
        if (node < n) {
            int beg = row_start[node], end = row_start[node + 1];
            for (int chunk = beg; chunk < end; chunk += 16) {
                int cdeg = min(end - chunk, 16);
                int s_l = (chunk + lid < end) ? csr_src[chunk + lid] : 0;
                int it = 0;
                for (; it + 3 < cdeg; it += 4) {
                    int se0 = __shfl(s_l, gbase + it);
                    int se1 = __shfl(s_l, gbase + it + 1);
                    int se2 = __shfl(s_l, gbase + it + 2);
                    int se3 = __shfl(s_l, gbase + it + 3);
                    float4 v0 = *(const float4*)&H[(size_t)se0 * 64 + c4];
                    float4 v1 = *(const float4*)&H[(size_t)se1 * 64 + c4];
                    float4 v2 = *(const float4*)&H[(size_t)se2 * 64 + c4];
                    float4 v3 = *(const float4*)&H[(size_t)se3 * 64 + c4];
                    acc.x += (v0.x + v1.x) + (v2.x + v3.x);
                    acc.y += (v0.y + v1.y) + (v2.y + v3.y);
                    acc.z += (v0.z + v1.z) + (v2.z + v3.z);
                    acc.w += (v0.w + v1.w) + (v2.w + v3.w);
                }
                for (; it < cdeg; it++) {
                    int se = __shfl(s_l, gbase + it);
                    float4 v = *(const float4*)&H[(size_t)se * 64 + c4];
                    acc.x += v.x; acc.y += v.y; acc.z += v.z; acc.w += v.w;
                }
            }
        }
        *(float4*)&Alds[r * 68 + c4] = acc;
    }
    __syncthreads();

    // GEMM phase
    const int r0 = (t >> 4) * 4, c0 = (t & 15) * 4;
    float4 acc0 = make_float4(0.f, 0.f, 0.f, 0.f), acc1 = acc0, acc2 = acc0, acc3 = acc0;
    #pragma unroll 2
    for (int k = 0; k < 64; k += 4) {
        float4 a0 = *(float4*)&Alds[(r0 + 0) * 68 + k];
        float4 a1 = *(float4*)&Alds[(r0 + 1) * 68 + k];
        float4 a2 = *(float4*)&Alds[(r0 + 2) * 68 + k];
        float4 a3 = *(float4*)&Alds[(r0 + 3) * 68 + k];
        float4 w0 = *(float4*)&Wlds[(k + 0) * 68 + c0];
        float4 w1 = *(float4*)&Wlds[(k + 1) * 68 + c0];
        float4 w2 = *(float4*)&Wlds[(k + 2) * 68 + c0];
        float4 w3 = *(float4*)&Wlds[(k + 3) * 68 + c0];
        MAC4(acc0, a0, w0, w1, w2, w3);
        MAC4(acc1, a1, w0, w1, w2, w3);
        MAC4(acc2, a2, w0, w1, w2, w3);
        MAC4(acc3, a3, w0, w1, w2, w3);
    }
    float4 w2c[5];
    #pragma unroll
    for (int j = 0; j < 5; j++) w2c[j] = *(const float4*)&Wfold[4096 + j * 64 + c0];
    const float4 cv4 = *(const float4*)&Wfold[4416 + c0];
    #define EC_STORE(i, acc)                                                        \
        { int row = base + r0 + i;                                                  \
          if (row < n) {                                                            \
              const float* bp = B5 + (size_t)row * 5;                               \
              float deg = (float)(row_start[row + 1] - row_start[row]);             \
              float4 q;                                                             \
              q.x = deg * cv4.x; q.y = deg * cv4.y;                                 \
              q.z = deg * cv4.z; q.w = deg * cv4.w;                                 \
              for (int j = 0; j < 5; j++) {                                         \
                  float b = bp[j];                                                  \
                  q.x = fmaf(b, w2c[j].x, q.x); q.y = fmaf(b, w2c[j].y, q.y);       \
                  q.z = fmaf(b, w2c[j].z, q.z); q.w = fmaf(b, w2c[j].w, q.w);       \
              }                                                                     \
              float4 r4;                                                            \
              r4.x = fmaxf(acc.x + q.x, 0.f); r4.y = fmaxf(acc.y + q.y, 0.f);       \
              r4.z = fmaxf(acc.z + q.z, 0.f); r4.w = fmaxf(acc.w + q.w, 0.f);       \
              *(float4*)&OUT[(size_t)row * 64 + c0] = r4; } }
    EC_STORE(0, acc0) EC_STORE(1, acc1) EC_STORE(2, acc2) EC_STORE(3, acc3)
    #undef EC_STORE
}

// ------- GAT GEMM (fp32 in, fp16 G out) + attention scores fused ------------
__global__ __launch_bounds__(TPB) void k_gemm_gat(const float* __restrict__ H, const float* __restrict__ W,
                                                  const float* __restrict__ att_src, const float* __restrict__ att_dst,
                                                  u32* __restrict__ Gh, float* __restrict__ asrc,
                                                  float* __restrict__ adst, int n) {
    __shared__ float Alds[64 * 68];
    __shared__ float Wlds[64 * 132];
    const int t = threadIdx.x;
    const int base = blockIdx.x * 64;
    {
        int r16 = t >> 4, cc = (t & 15) * 4;
        #pragma unroll
        for (int rep = 0; rep < 4; rep++) {
            int r = rep * 16 + r16;
            int row = base + r;
            float4 v = make_float4(0.f, 0.f, 0.f, 0.f);
            if (row < n) v = *(const float4*)&H[(size_t)row * 64 + cc];
            *(float4*)&Alds[r * 68 + cc] = v;
        }
        #pragma unroll
        for (int rep = 0; rep < 8; rep++) {
            int idx4 = (rep * 256 + t) * 4;
            int r = idx4 >> 7, c = idx4 & 127;
            *(float4*)&Wlds[r * 132 + c] = *(const float4*)&W[r * 128 + c];
        }
    }
    __syncthreads();

    const int r0 = (t >> 4) * 4, c0 = (t & 15) * 4;
    float4 p00 = make_float4(0.f, 0.f, 0.f, 0.f), p01 = p00, p02 = p00, p03 = p00;
    float4 p10 = p00, p11 = p00, p12 = p00, p13 = p00;
    #pragma unroll 2
    for (int k = 0; k < 64; k += 4) {
        float4 a0 = *(float4*)&Alds[(r0 + 0) * 68 + k];
        float4 a1 = *(float4*)&Alds[(r0 + 1) * 68 + k];
        float4 a2 = *(float4*)&Alds[(r0 + 2) * 68 + k];
        float4 a3 = *(float4*)&Alds[(r0 + 3) * 68 + k];
        float4 u0 = *(float4*)&Wlds[(k + 0) * 132 + c0];
        float4 u1 = *(float4*)&Wlds[(k + 1) * 132 + c0];
        float4 u2 = *(float4*)&Wlds[(k + 2) * 132 + c0];
        float4 u3 = *(float4*)&Wlds[(k + 3) * 132 + c0];
        MAC4(p00, a0, u0, u1, u2, u3);
        MAC4(p01, a1, u0, u1, u2, u3);
        MAC4(p02, a2, u0, u1, u2, u3);
        MAC4(p03, a3, u0, u1, u2, u3);
        float4 v0 = *(float4*)&Wlds[(k + 0) * 132 + 64 + c0];
        float4 v1 = *(float4*)&Wlds[(k + 1) * 132 + 64 + c0];
        float4 v2 = *(float4*)&Wlds[(k + 2) * 132 + 64 + c0];
        float4 v3 = *(float4*)&Wlds[(k + 3) * 132 + 64 + c0];
        MAC4(p10, a0, v0, v1, v2, v3);
        MAC4(p11, a1, v0, v1, v2, v3);
        MAC4(p12, a2, v0, v1, v2, v3);
        MAC4(p13, a3, v0, v1, v2, v3);
    }
    const float4 as0 = *(const float4*)&att_src[c0];
    const float4 as1 = *(const float4*)&att_src[64 + c0];
    const float4 ad0 = *(const float4*)&att_dst[c0];
    const float4 ad1 = *(const float4*)&att_dst[64 + c0];
    #define DOT4(a, b) (a.x * b.x + a.y * b.y + a.z * b.z + a.w * b.w)
    #define GAT_ROW(i, h0, h1)                                                      \
        { int row = base + r0 + i;                                                  \
          float s0 = DOT4(h0, as0), s1 = DOT4(h1, as1);                             \
          float d0 = DOT4(h0, ad0), d1 = DOT4(h1, ad1);                             \
          s0 += __shfl_xor(s0, 1); s1 += __shfl_xor(s1, 1);                         \
          d0 += __shfl_xor(d0, 1); d1 += __shfl_xor(d1, 1);                         \
          s0 += __shfl_xor(s0, 2); s1 += __shfl_xor(s1, 2);                         \
          d0 += __shfl_xor(d0, 2); d1 += __shfl_xor(d1, 2);                         \
          s0 += __shfl_xor(s0, 4); s1 += __shfl_xor(s1, 4);                         \
          d0 += __shfl_xor(d0, 4); d1 += __shfl_xor(d1, 4);                         \
          s0 += __shfl_xor(s0, 8); s1 += __shfl_xor(s1, 8);                         \
          d0 += __shfl_xor(d0, 8); d1 += __shfl_xor(d1, 8);                         \
          if (row < n) {                                                            \
              uint2 g0; g0.x = f16pack2(h0.x, h0.y); g0.y = f16pack2(h0.z, h0.w);   \
              uint2 g1; g1.x = f16pack2(h1.x, h1.y); g1.y = f16pack2(h1.z, h1.w);   \
              *(uint2*)&Gh[(size_t)row * 64 + (c0 >> 1)] = g0;                      \
              *(uint2*)&Gh[(size_t)row * 64 + 32 + (c0 >> 1)] = g1;                 \
              if ((t & 15) == 0) {                                                  \
                  float2 sv; sv.x = s0; sv.y = s1;                                  \
                  float2 dv; dv.x = d0; dv.y = d1;                                  \
                  *(float2*)&asrc[(size_t)row * 2] = sv;                            \
                  *(float2*)&adst[(size_t)row * 2] = dv; } } }
    GAT_ROW(0, p00, p10) GAT_ROW(1, p01, p11) GAT_ROW(2, p02, p12) GAT_ROW(3, p03, p13)
    #undef GAT_ROW
    #undef DOT4
}

// ----- GAT aggregation: fp16 G; one node per 16-lane group; head=lid>>3 -----
// Gh row = 128 halves = 64 u32 (head0 u32 0..31, head1 32..63).
// Lane lid loads uint4 at u32 offset lid*4 -> 8 cols of its head.
__global__ __launch_bounds__(TPB) void k_gat_agg(const u32* __restrict__ Gh, const int* __restrict__ row_start,
                                                 const int* __restrict__ csr_src, const float* __restrict__ asrc,
                                                 const float* __restrict__ adst, const float* __restrict__ bgat,
                                                 float* __restrict__ OUT, int n) {
    const int node = blockIdx.x * 16 + (threadIdx.x >> 4);
    if (node >= n) return;
    const int lane = threadIdx.x & 63;
    const int lid = lane & 15;
    const int gbase = lane & 48;
    const int head = lid >> 3;
    const int u4 = lid * 4;
    const int beg = row_start[node], end = row_start[node + 1];
    const float2 adv = *(const float2*)&adst[(size_t)node * 2];
    float m0 = -INFINITY, m1 = -INFINITY, d0 = 0.f, d1 = 0.f;
    float A[8] = {0.f, 0.f, 0.f, 0.f, 0.f, 0.f, 0.f, 0.f};
    for (int chunk = beg; chunk < end; chunk += 16) {
        int cdeg = min(end - chunk, 16);
        bool valid = (lid < cdeg);
        int s_l = valid ? csr_src[chunk + lid] : 0;
        float al0 = -INFINITY, al1 = -INFINITY;
        if (valid) {
            float2 av = *(const float2*)&asrc[(size_t)s_l * 2];
            float t0 = av.x + adv.x, t1 = av.y + adv.y;
            al0 = (t0 > 0.f) ? t0 : 0.2f * t0;
            al1 = (t1 > 0.f) ? t1 : 0.2f * t1;
        }
        float cm0 = al0, cm1 = al1;
        #pragma unroll
        for (int off = 1; off < 16; off <<= 1) {
            cm0 = fmaxf(cm0, __shfl_xor(cm0, off));
            cm1 = fmaxf(cm1, __shfl_xor(cm1, off));
        }
        float nm0 = fmaxf(m0, cm0), nm1 = fmaxf(m1, cm1);
        float sc0 = __expf(m0 - nm0), sc1 = __expf(m1 - nm1);  // 0 on first chunk
        float w0 = valid ? __expf(al0 - nm0) : 0.f;
        float w1 = valid ? __expf(al1 - nm1) : 0.f;
        float cd0 = w0, cd1 = w1;
        #pragma unroll
        for (int off = 1; off < 16; off <<= 1) {
            cd0 += __shfl_xor(cd0, off);
            cd1 += __shfl_xor(cd1, off);
        }
        d0 = d0 * sc0 + cd0;
        d1 = d1 * sc1 + cd1;
        float scsel = head ? sc1 : sc0;
        #pragma unroll
        for (int j = 0; j < 8; j++) A[j] *= scsel;
        m0 = nm0; m1 = nm1;
        int it = 0;
        for (; it + 1 < cdeg; it += 2) {
            int sa = __shfl(s_l, gbase + it);
            int sb = __shfl(s_l, gbase + it + 1);
            float w0a = __shfl(w0, gbase + it), w1a = __shfl(w1, gbase + it);
            float w0b = __shfl(w0, gbase + it + 1), w1b = __shfl(w1, gbase + it + 1);
            float wa = head ? w1a : w0a;
            float wb = head ? w1b : w0b;
            uint4 va = *(const uint4*)&Gh[(size_t)sa * 64 + u4];
            uint4 vb = *(const uint4*)&Gh[(size_t)sb * 64 + u4];
            fma_f16x8(A, va, wa);
            fma_f16x8(A, vb, wb);
        }
        if (it < cdeg) {
            int sa = __shfl(s_l, gbase + it);
            float w0a = __shfl(w0, gbase + it), w1a = __shfl(w1, gbase + it);
            float wa = head ? w1a : w0a;
            uint4 va = *(const uint4*)&Gh[(size_t)sa * 64 + u4];
            fma_f16x8(A, va, wa);
        }
    }
    float rh = 0.5f / ((head ? d1 : d0) + 1e-16f);
    #pragma unroll
    for (int j = 0; j < 8; j++) {
        A[j] *= rh;
        A[j] += __shfl_xor(A[j], 8);   // combine the two heads
    }
    if (head == 0) {
        int cb = (lid & 7) * 8;
        const float4 bg0 = *(const float4*)&bgat[cb];
        const float4 bg1 = *(const float4*)&bgat[cb + 4];
        float4 o0; o0.x = A[0] + bg0.x; o0.y = A[1] + bg0.y; o0.z = A[2] + bg0.z; o0.w = A[3] + bg0.w;
        float4 o1; o1.x = A[4] + bg1.x; o1.y = A[5] + bg1.y; o1.z = A[6] + bg1.z; o1.w = A[7] + bg1.w;
        float* op = &OUT[(size_t)node * 64 + cb];
        *(float4*)op = o0;
        *(float4*)(op + 4) = o1;
    }
}

extern "C" void kernel_launch(void* const* d_in, const int* in_sizes, int n_in,
                              void* d_out, int out_size, void* d_ws, size_t ws_size,
                              hipStream_t stream) {
    const float* x   = (const float*)d_in[0];
    const int*   ei  = (const int*)d_in[1];
    const float* ea  = (const float*)d_in[2];
    const int N = in_sizes[0] / 64;
    const int E = in_sizes[1] / 2;
    const int* src = ei;
    const int* dst = ei + E;

    const float* wn[3] = {(const float*)d_in[3],  (const float*)d_in[9],  (const float*)d_in[15]};
    const float* bn[3] = {(const float*)d_in[4],  (const float*)d_in[10], (const float*)d_in[16]};
    const float* we[3] = {(const float*)d_in[5],  (const float*)d_in[11], (const float*)d_in[17]};
    const float* be[3] = {(const float*)d_in[6],  (const float*)d_in[12], (const float*)d_in[18]};
    const float* wc[3] = {(const float*)d_in[7],  (const float*)d_in[13], (const float*)d_in[19]};
    const float* bc[3] = {(const float*)d_in[8],  (const float*)d_in[14], (const float*)d_in[20]};
    const float* wgat    = (const float*)d_in[21];
    const float* att_src = (const float*)d_in[22];
    const float* att_dst = (const float*)d_in[23];
    const float* bgat    = (const float*)d_in[24];

    // workspace carve-up (256B aligned)
    char* ws = (char*)d_ws;
    size_t off = 0;
    auto alloc = [&](size_t bytes) -> void* {
        void* p = ws + off;
        off = (off + bytes + 255) & ~(size_t)255;
        return p;
    };
    int*   row_start = (int*)alloc((size_t)(N + 1) * 4);
    int*   cursor    = (int*)alloc((size_t)N * 4);
    int*   partials  = (int*)alloc(1024 * 4);
    int*   csr_e     = (int*)alloc((size_t)E * 4);
    int*   csr_src   = (int*)alloc((size_t)E * 4);
    float* Wc        = (float*)alloc((size_t)3 * 4480 * 4);   // per layer: W1|W2|cv
    float* B5        = (float*)alloc((size_t)N * 5 * 4);
    float* bufH0     = (float*)alloc((size_t)N * 64 * 4);     // h ping (fp32)
    float* bufH1     = (float*)alloc((size_t)N * 64 * 4);     // h pong (fp32)
    u32*   Gh        = (u32*)alloc((size_t)N * 64 * 4);       // fp16 G [N][128]
    float* asrc      = (float*)alloc((size_t)N * 2 * 4);
    float* adst      = (float*)alloc((size_t)N * 2 * 4);
    float* out = (float*)d_out;

    const int nbN = (N + TPB - 1) / TPB;
    const int nbE = (E + TPB - 1) / TPB;
    const int nodeBlocks = (N + 3) / 4;
    const int grpBlocks = (N + 15) / 16;
    const int tiles = (N + 63) / 64;

    // ---- fold weights ----
    for (int l = 0; l < 3; l++) {
        float* W1 = Wc + l * 4480;
        k_combine<<<1, TPB, 0, stream>>>(wn[l], bn[l], we[l], be[l], wc[l], bc[l],
                                         W1, W1 + 4096, W1 + 4416);
    }

    // ---- build CSR by dst ----
    hipMemsetAsync(row_start, 0, (size_t)N * 4, stream);
    k_hist<<<nbE, TPB, 0, stream>>>(dst, row_start, E);
    k_scan1<<<nbN, TPB, 0, stream>>>(row_start, partials, N);
    k_scan2<<<1, 1024, 0, stream>>>(partials, nbN);
    k_scan3<<<nbN, TPB, 0, stream>>>(row_start, partials, cursor, N, E);
    k_scatter<<<nbE, TPB, 0, stream>>>(src, dst, cursor, csr_e, csr_src, E);

    // ---- one-time edge-attr aggregation ----
    k_aggB5<<<nodeBlocks, TPB, 0, stream>>>(row_start, csr_e, ea, B5, N);

    // ---- 3 fused edge-conv layers ----
    k_ec_fused<<<tiles, TPB, 0, stream>>>(x,     row_start, csr_src, Wc,            B5, bufH0, N);
    k_ec_fused<<<tiles, TPB, 0, stream>>>(bufH0, row_start, csr_src, Wc + 4480,     B5, bufH1, N);
    k_ec_fused<<<tiles, TPB, 0, stream>>>(bufH1, row_start, csr_src, Wc + 2 * 4480, B5, bufH0, N);

    // ---- GAT ----
    k_gemm_gat<<<tiles, TPB, 0, stream>>>(bufH0, wgat, att_src, att_dst, Gh, asrc, adst, N);
    k_gat_agg<<<grpBlocks, TPB, 0, stream>>>(Gh, row_start, csr_src, asrc, adst, bgat, out, N);
}